// Round 1
// baseline (418.886 us; speedup 1.0000x reference)
//
#include <hip/hip_runtime.h>
#include <hip/hip_bf16.h>

#define DEV __device__ __forceinline__

typedef __attribute__((ext_vector_type(8))) short short8;
typedef __attribute__((ext_vector_type(4))) float f32x4;

constexpr int B = 4, N = 2048, DIM = 512, H = 8, DH = 64;
constexpr int INNER = H * DH;          // 512
constexpr int M = B * N;               // 8192
constexpr int BH = B * H;              // 32
constexpr float SCALE = 0.125f;        // DH^-0.5

// ---- workspace layout (bf16 elements) ----
constexpr size_t OFF_WQKVT = 0;                               // [1536][512]  w_qkv^T
constexpr size_t OFF_WOUTT = OFF_WQKVT + (size_t)1536 * 512;  // [512][512]   w_out^T
constexpr size_t OFF_QT    = OFF_WOUTT + (size_t)512 * 512;   // [32][2048][128]  Q~ (scaled)
constexpr size_t OFF_KT    = OFF_QT + (size_t)BH * N * 128;   // [32][2048][128]  K~
constexpr size_t OFF_VT    = OFF_KT + (size_t)BH * N * 128;   // [32][64][2048]   V transposed
constexpr size_t OFF_AO    = OFF_VT + (size_t)BH * DH * N;    // [8192][512]  attention out

DEV short f2b(float f) {
    __hip_bfloat16 h = __float2bfloat16(f);
    return __builtin_bit_cast(short, h);
}

// ---------------- prep: transpose weights to bf16 [col][k] ----------------
__global__ void prep_kernel(const float* __restrict__ wqkv,
                            const float* __restrict__ wout,
                            __hip_bfloat16* __restrict__ ws) {
    __hip_bfloat16* wqkvT = ws + OFF_WQKVT;
    __hip_bfloat16* woutT = ws + OFF_WOUTT;
    int tid = blockIdx.x * blockDim.x + threadIdx.x;
    const int total1 = 512 * 1536 / 4;   // float4s of w_qkv
    const int total2 = 512 * 512 / 4;    // float4s of w_out
    for (int i = tid; i < total1 + total2; i += gridDim.x * blockDim.x) {
        if (i < total1) {
            int k  = i / 384;
            int c4 = (i % 384) * 4;
            float4 v = ((const float4*)wqkv)[i];
            wqkvT[(size_t)(c4 + 0) * 512 + k] = __float2bfloat16(v.x);
            wqkvT[(size_t)(c4 + 1) * 512 + k] = __float2bfloat16(v.y);
            wqkvT[(size_t)(c4 + 2) * 512 + k] = __float2bfloat16(v.z);
            wqkvT[(size_t)(c4 + 3) * 512 + k] = __float2bfloat16(v.w);
        } else {
            int j  = i - total1;
            int k  = j / 128;
            int c4 = (j % 128) * 4;
            float4 v = ((const float4*)wout)[j];
            woutT[(size_t)(c4 + 0) * 512 + k] = __float2bfloat16(v.x);
            woutT[(size_t)(c4 + 1) * 512 + k] = __float2bfloat16(v.y);
            woutT[(size_t)(c4 + 2) * 512 + k] = __float2bfloat16(v.z);
            woutT[(size_t)(c4 + 3) * 512 + k] = __float2bfloat16(v.w);
        }
    }
}

// ---------------- GEMM1: qkv = {x,bias} @ w_qkv, scatter to QT/KT/VT ----------------
// grid.x = 64 (m tiles of 128), grid.y = 20 (0..11: x, all 1536 cols; 12..19: bias, cols 0..1023)
__global__ __launch_bounds__(256) void gemm_qkv(const float* __restrict__ x,
                                                const float* __restrict__ bias,
                                                __hip_bfloat16* __restrict__ ws) {
    int mt = blockIdx.x, yt = blockIdx.y;
    bool src_is_bias = (yt >= 12);
    int nt = src_is_bias ? yt - 12 : yt;
    const float* A = src_is_bias ? bias : x;
    const __hip_bfloat16* Bt = ws + OFF_WQKVT;
    int m0 = mt * 128, n0 = nt * 128;

    __shared__ __align__(16) short As[128][72];
    __shared__ __align__(16) short Bs[128][72];

    int tid  = threadIdx.x;
    int wave = tid >> 6, lane = tid & 63;
    int wrow = wave >> 1, wcol = wave & 1;
    int lg = lane >> 4, li = lane & 15;

    f32x4 acc[4][4] = {};

    for (int k0 = 0; k0 < 512; k0 += 64) {
#pragma unroll
        for (int r = 0; r < 4; ++r) {
            int idx = (tid + r * 256) * 8;
            int row = idx >> 6, kk = idx & 63;
            const float* srcA = A + (size_t)(m0 + row) * 512 + k0 + kk;
            float4 v0 = ((const float4*)srcA)[0];
            float4 v1 = ((const float4*)srcA)[1];
            short8 sv;
            sv[0] = f2b(v0.x); sv[1] = f2b(v0.y); sv[2] = f2b(v0.z); sv[3] = f2b(v0.w);
            sv[4] = f2b(v1.x); sv[5] = f2b(v1.y); sv[6] = f2b(v1.z); sv[7] = f2b(v1.w);
            *(short8*)(&As[row][kk]) = sv;
            const __hip_bfloat16* srcB = Bt + (size_t)(n0 + row) * 512 + k0 + kk;
            *(short8*)(&Bs[row][kk]) = *(const short8*)srcB;
        }
        __syncthreads();
#pragma unroll
        for (int ks = 0; ks < 2; ++ks) {
            short8 af[4], bf[4];
#pragma unroll
            for (int m = 0; m < 4; ++m)
                af[m] = *(const short8*)(&As[wrow * 64 + m * 16 + li][ks * 32 + lg * 8]);
#pragma unroll
            for (int n = 0; n < 4; ++n)
                bf[n] = *(const short8*)(&Bs[wcol * 64 + n * 16 + li][ks * 32 + lg * 8]);
#pragma unroll
            for (int m = 0; m < 4; ++m)
#pragma unroll
                for (int n = 0; n < 4; ++n)
                    acc[m][n] = __builtin_amdgcn_mfma_f32_16x16x32_bf16(af[m], bf[n], acc[m][n], 0, 0, 0);
        }
        __syncthreads();
    }

    __hip_bfloat16* QT = ws + OFF_QT;
    __hip_bfloat16* KT = ws + OFF_KT;
    __hip_bfloat16* VT = ws + OFF_VT;
    int qkoff = src_is_bias ? 64 : 0;
#pragma unroll
    for (int m = 0; m < 4; ++m)
#pragma unroll
        for (int n = 0; n < 4; ++n)
#pragma unroll
            for (int j = 0; j < 4; ++j) {
                int row = m0 + wrow * 64 + m * 16 + lg * 4 + j;
                int col = n0 + wcol * 64 + n * 16 + li;
                float v = acc[m][n][j];
                int b = row >> 11, nn = row & 2047;
                if (col < 512) {
                    int h = col >> 6, d = col & 63;
                    QT[((size_t)(b * H + h) * N + nn) * 128 + d + qkoff] = __float2bfloat16(v * SCALE);
                } else if (col < 1024) {
                    int c = col - 512; int h = c >> 6, d = c & 63;
                    KT[((size_t)(b * H + h) * N + nn) * 128 + d + qkoff] = __float2bfloat16(v);
                } else {
                    int c = col - 1024; int h = c >> 6, d = c & 63;
                    VT[((size_t)(b * H + h) * DH + d) * N + nn] = __float2bfloat16(v);
                }
            }
}

// ---------------- flash attention ----------------
// grid: (N/64, BH). block 256 = 4 waves, each wave owns 16 q rows. KV tile = 64.
__global__ __launch_bounds__(256) void attn_kernel(__hip_bfloat16* __restrict__ ws) {
    int bh = blockIdx.y;
    int wave = threadIdx.x >> 6, lane = threadIdx.x & 63;
    int lg = lane >> 4, li = lane & 15;
    int qr0 = blockIdx.x * 64 + wave * 16;

    const short* QT = (const short*)(ws + OFF_QT) + (size_t)bh * N * 128;
    const short* KT = (const short*)(ws + OFF_KT) + (size_t)bh * N * 128;
    const short* VT = (const short*)(ws + OFF_VT) + (size_t)bh * DH * N;

    __shared__ __align__(16) short p_lds[4][16][72];

    short8 qf[4];
#pragma unroll
    for (int kc = 0; kc < 4; ++kc)
        qf[kc] = *(const short8*)(QT + (size_t)(qr0 + li) * 128 + kc * 32 + lg * 8);

    float m_run[4] = {-1e30f, -1e30f, -1e30f, -1e30f};
    float l_run[4] = {0.f, 0.f, 0.f, 0.f};
    f32x4 o[4] = {};

    for (int kv0 = 0; kv0 < N; kv0 += 64) {
        f32x4 s[4] = {};
#pragma unroll
        for (int cf = 0; cf < 4; ++cf) {
#pragma unroll
            for (int kc = 0; kc < 4; ++kc) {
                short8 kf = *(const short8*)(KT + (size_t)(kv0 + cf * 16 + li) * 128 + kc * 32 + lg * 8);
                s[cf] = __builtin_amdgcn_mfma_f32_16x16x32_bf16(qf[kc], kf, s[cf], 0, 0, 0);
            }
        }
        // row max over 64 cols (4 frags x 16 lanes)
        float pmax[4], psum[4];
#pragma unroll
        for (int j = 0; j < 4; ++j) {
            float v = fmaxf(fmaxf(s[0][j], s[1][j]), fmaxf(s[2][j], s[3][j]));
#pragma unroll
            for (int off = 1; off < 16; off <<= 1) v = fmaxf(v, __shfl_xor(v, off));
            pmax[j] = v;
        }
        float mnew[4], alpha[4];
#pragma unroll
        for (int j = 0; j < 4; ++j) {
            mnew[j]  = fmaxf(m_run[j], pmax[j]);
            alpha[j] = __expf(m_run[j] - mnew[j]);
            psum[j]  = 0.f;
        }
#pragma unroll
        for (int cf = 0; cf < 4; ++cf)
#pragma unroll
            for (int j = 0; j < 4; ++j) {
                float p = __expf(s[cf][j] - mnew[j]);
                s[cf][j] = p;
                psum[j] += p;
            }
#pragma unroll
        for (int j = 0; j < 4; ++j) {
#pragma unroll
            for (int off = 1; off < 16; off <<= 1) psum[j] += __shfl_xor(psum[j], off);
            l_run[j] = l_run[j] * alpha[j] + psum[j];
            m_run[j] = mnew[j];
        }
#pragma unroll
        for (int vc = 0; vc < 4; ++vc)
#pragma unroll
            for (int j = 0; j < 4; ++j) o[vc][j] *= alpha[j];

        // P (C-layout) -> LDS -> A-layout fragments
#pragma unroll
        for (int cf = 0; cf < 4; ++cf)
#pragma unroll
            for (int j = 0; j < 4; ++j)
                p_lds[wave][lg * 4 + j][cf * 16 + li] = f2b(s[cf][j]);

        short8 pf0 = *(const short8*)(&p_lds[wave][li][lg * 8]);
        short8 pf1 = *(const short8*)(&p_lds[wave][li][32 + lg * 8]);
#pragma unroll
        for (int vc = 0; vc < 4; ++vc) {
            const short* vb = VT + (size_t)(vc * 16 + li) * N + kv0;
            short8 vf0 = *(const short8*)(vb + lg * 8);
            short8 vf1 = *(const short8*)(vb + 32 + lg * 8);
            o[vc] = __builtin_amdgcn_mfma_f32_16x16x32_bf16(pf0, vf0, o[vc], 0, 0, 0);
            o[vc] = __builtin_amdgcn_mfma_f32_16x16x32_bf16(pf1, vf1, o[vc], 0, 0, 0);
        }
    }

    __hip_bfloat16* AO = ws + OFF_AO;
    int b = bh >> 3, h = bh & 7;
#pragma unroll
    for (int vc = 0; vc < 4; ++vc)
#pragma unroll
        for (int j = 0; j < 4; ++j) {
            float v = o[vc][j] / l_run[j];
            int nrow = qr0 + lg * 4 + j;
            int col  = h * 64 + vc * 16 + li;
            AO[(size_t)(b * N + nrow) * INNER + col] = __float2bfloat16(v);
        }
}

// ---------------- GEMM3: out = AO @ w_out + b_out (f32 out) ----------------
__global__ __launch_bounds__(256) void gemm_out(const __hip_bfloat16* __restrict__ ws_c,
                                                const float* __restrict__ bout,
                                                float* __restrict__ out) {
    const __hip_bfloat16* AO = ws_c + OFF_AO;
    const __hip_bfloat16* Bt = ws_c + OFF_WOUTT;
    int m0 = blockIdx.x * 128, n0 = blockIdx.y * 128;

    __shared__ __align__(16) short As[128][72];
    __shared__ __align__(16) short Bs[128][72];

    int tid  = threadIdx.x;
    int wave = tid >> 6, lane = tid & 63;
    int wrow = wave >> 1, wcol = wave & 1;
    int lg = lane >> 4, li = lane & 15;

    f32x4 acc[4][4] = {};

    for (int k0 = 0; k0 < 512; k0 += 64) {
#pragma unroll
        for (int r = 0; r < 4; ++r) {
            int idx = (tid + r * 256) * 8;
            int row = idx >> 6, kk = idx & 63;
            *(short8*)(&As[row][kk]) = *(const short8*)(AO + (size_t)(m0 + row) * 512 + k0 + kk);
            *(short8*)(&Bs[row][kk]) = *(const short8*)(Bt + (size_t)(n0 + row) * 512 + k0 + kk);
        }
        __syncthreads();
#pragma unroll
        for (int ks = 0; ks < 2; ++ks) {
            short8 af[4], bf[4];
#pragma unroll
            for (int m = 0; m < 4; ++m)
                af[m] = *(const short8*)(&As[wrow * 64 + m * 16 + li][ks * 32 + lg * 8]);
#pragma unroll
            for (int n = 0; n < 4; ++n)
                bf[n] = *(const short8*)(&Bs[wcol * 64 + n * 16 + li][ks * 32 + lg * 8]);
#pragma unroll
            for (int m = 0; m < 4; ++m)
#pragma unroll
                for (int n = 0; n < 4; ++n)
                    acc[m][n] = __builtin_amdgcn_mfma_f32_16x16x32_bf16(af[m], bf[n], acc[m][n], 0, 0, 0);
        }
        __syncthreads();
    }
#pragma unroll
    for (int m = 0; m < 4; ++m)
#pragma unroll
        for (int n = 0; n < 4; ++n)
#pragma unroll
            for (int j = 0; j < 4; ++j) {
                int row = m0 + wrow * 64 + m * 16 + lg * 4 + j;
                int col = n0 + wcol * 64 + n * 16 + li;
                out[(size_t)row * 512 + col] = acc[m][n][j] + bout[col];
            }
}

extern "C" void kernel_launch(void* const* d_in, const int* in_sizes, int n_in,
                              void* d_out, int out_size, void* d_ws, size_t ws_size,
                              hipStream_t stream) {
    const float* x    = (const float*)d_in[0];
    const float* bias = (const float*)d_in[1];
    const float* wqkv = (const float*)d_in[2];
    const float* wout = (const float*)d_in[3];
    const float* bout = (const float*)d_in[4];
    float* out = (float*)d_out;
    __hip_bfloat16* ws = (__hip_bfloat16*)d_ws;

    hipLaunchKernelGGL(prep_kernel, dim3(512), dim3(256), 0, stream, wqkv, wout, ws);
    hipLaunchKernelGGL(gemm_qkv, dim3(64, 20), dim3(256), 0, stream, x, bias, ws);
    hipLaunchKernelGGL(attn_kernel, dim3(N / 64, BH), dim3(256), 0, stream, ws);
    hipLaunchKernelGGL(gemm_out, dim3(64, 4), dim3(256), 0, stream, (const __hip_bfloat16*)ws, bout, out);
}

// Round 2
// 152.589 us; speedup vs baseline: 2.7452x; 2.7452x over previous
//
#include <hip/hip_runtime.h>
#include <hip/hip_bf16.h>

#define DEV __device__ __forceinline__

typedef __attribute__((ext_vector_type(8))) short short8;
typedef __attribute__((ext_vector_type(4))) short sv4;
typedef __attribute__((ext_vector_type(4))) float f32x4;

constexpr int B = 4, N = 2048, DIM = 512, H = 8, DH = 64;
constexpr int INNER = H * DH;          // 512
constexpr int BH = B * H;              // 32
constexpr float SCALE = 0.125f;        // DH^-0.5

// ---- workspace layout (bf16 elements) ----
constexpr size_t OFF_WQKVT = 0;                               // [1536][512]  w_qkv^T
constexpr size_t OFF_WOUTT = OFF_WQKVT + (size_t)1536 * 512;  // [512][512]   w_out^T
constexpr size_t OFF_QT    = OFF_WOUTT + (size_t)512 * 512;   // [32][2048][128]  Q~ (scaled)
constexpr size_t OFF_KT    = OFF_QT + (size_t)BH * N * 128;   // [32][2048][128]  K~
constexpr size_t OFF_VT    = OFF_KT + (size_t)BH * N * 128;   // [32][64][2048]   V transposed
constexpr size_t OFF_AO    = OFF_VT + (size_t)BH * DH * N;    // [8192][512]  attention out

DEV short f2b(float f) {
    __hip_bfloat16 h = __float2bfloat16(f);
    return __builtin_bit_cast(short, h);
}

DEV void gload16(const void* g, void* l) {
    __builtin_amdgcn_global_load_lds(
        (const __attribute__((address_space(1))) unsigned int*)g,
        (__attribute__((address_space(3))) unsigned int*)l, 16, 0, 0);
}

// ---------------- prep: transpose weights to bf16 [col][k] ----------------
__global__ void prep_kernel(const float* __restrict__ wqkv,
                            const float* __restrict__ wout,
                            __hip_bfloat16* __restrict__ ws) {
    __hip_bfloat16* wqkvT = ws + OFF_WQKVT;
    __hip_bfloat16* woutT = ws + OFF_WOUTT;
    int tid = blockIdx.x * blockDim.x + threadIdx.x;
    const int total1 = 512 * 1536 / 4;
    const int total2 = 512 * 512 / 4;
    for (int i = tid; i < total1 + total2; i += gridDim.x * blockDim.x) {
        if (i < total1) {
            int k  = i / 384;
            int c4 = (i % 384) * 4;
            float4 v = ((const float4*)wqkv)[i];
            wqkvT[(size_t)(c4 + 0) * 512 + k] = __float2bfloat16(v.x);
            wqkvT[(size_t)(c4 + 1) * 512 + k] = __float2bfloat16(v.y);
            wqkvT[(size_t)(c4 + 2) * 512 + k] = __float2bfloat16(v.z);
            wqkvT[(size_t)(c4 + 3) * 512 + k] = __float2bfloat16(v.w);
        } else {
            int j  = i - total1;
            int k  = j / 128;
            int c4 = (j % 128) * 4;
            float4 v = ((const float4*)wout)[j];
            woutT[(size_t)(c4 + 0) * 512 + k] = __float2bfloat16(v.x);
            woutT[(size_t)(c4 + 1) * 512 + k] = __float2bfloat16(v.y);
            woutT[(size_t)(c4 + 2) * 512 + k] = __float2bfloat16(v.z);
            woutT[(size_t)(c4 + 3) * 512 + k] = __float2bfloat16(v.w);
        }
    }
}

// ---------------- GEMM1: qkv = {x,bias} @ w_qkv, scatter to QT/KT/VT ----------------
__global__ __launch_bounds__(256) void gemm_qkv(const float* __restrict__ x,
                                                const float* __restrict__ bias,
                                                __hip_bfloat16* __restrict__ ws) {
    int mt = blockIdx.x, yt = blockIdx.y;
    bool src_is_bias = (yt >= 12);
    int nt = src_is_bias ? yt - 12 : yt;
    const float* A = src_is_bias ? bias : x;
    const __hip_bfloat16* Bt = ws + OFF_WQKVT;
    int m0 = mt * 128, n0 = nt * 128;

    __shared__ __align__(16) short As[128][72];
    __shared__ __align__(16) short Bs[128][72];

    int tid  = threadIdx.x;
    int wave = tid >> 6, lane = tid & 63;
    int wrow = wave >> 1, wcol = wave & 1;
    int lg = lane >> 4, li = lane & 15;

    f32x4 acc[4][4] = {};

    for (int k0 = 0; k0 < 512; k0 += 64) {
#pragma unroll
        for (int r = 0; r < 4; ++r) {
            int idx = (tid + r * 256) * 8;
            int row = idx >> 6, kk = idx & 63;
            const float* srcA = A + (size_t)(m0 + row) * 512 + k0 + kk;
            float4 v0 = ((const float4*)srcA)[0];
            float4 v1 = ((const float4*)srcA)[1];
            short8 sv;
            sv[0] = f2b(v0.x); sv[1] = f2b(v0.y); sv[2] = f2b(v0.z); sv[3] = f2b(v0.w);
            sv[4] = f2b(v1.x); sv[5] = f2b(v1.y); sv[6] = f2b(v1.z); sv[7] = f2b(v1.w);
            *(short8*)(&As[row][kk]) = sv;
            const __hip_bfloat16* srcB = Bt + (size_t)(n0 + row) * 512 + k0 + kk;
            *(short8*)(&Bs[row][kk]) = *(const short8*)srcB;
        }
        __syncthreads();
#pragma unroll
        for (int ks = 0; ks < 2; ++ks) {
            short8 af[4], bf[4];
#pragma unroll
            for (int m = 0; m < 4; ++m)
                af[m] = *(const short8*)(&As[wrow * 64 + m * 16 + li][ks * 32 + lg * 8]);
#pragma unroll
            for (int n = 0; n < 4; ++n)
                bf[n] = *(const short8*)(&Bs[wcol * 64 + n * 16 + li][ks * 32 + lg * 8]);
#pragma unroll
            for (int m = 0; m < 4; ++m)
#pragma unroll
                for (int n = 0; n < 4; ++n)
                    acc[m][n] = __builtin_amdgcn_mfma_f32_16x16x32_bf16(af[m], bf[n], acc[m][n], 0, 0, 0);
        }
        __syncthreads();
    }

    __hip_bfloat16* QT = ws + OFF_QT;
    __hip_bfloat16* KT = ws + OFF_KT;
    __hip_bfloat16* VT = ws + OFF_VT;
    int qkoff = src_is_bias ? 64 : 0;
#pragma unroll
    for (int m = 0; m < 4; ++m)
#pragma unroll
        for (int n = 0; n < 4; ++n)
#pragma unroll
            for (int j = 0; j < 4; ++j) {
                int row = m0 + wrow * 64 + m * 16 + lg * 4 + j;
                int col = n0 + wcol * 64 + n * 16 + li;
                float v = acc[m][n][j];
                int b = row >> 11, nn = row & 2047;
                if (col < 512) {
                    int h = col >> 6, d = col & 63;
                    QT[((size_t)(b * H + h) * N + nn) * 128 + d + qkoff] = __float2bfloat16(v * SCALE);
                } else if (col < 1024) {
                    int c = col - 512; int h = c >> 6, d = c & 63;
                    KT[((size_t)(b * H + h) * N + nn) * 128 + d + qkoff] = __float2bfloat16(v);
                } else {
                    int c = col - 1024; int h = c >> 6, d = c & 63;
                    VT[((size_t)(b * H + h) * DH + d) * N + nn] = __float2bfloat16(v);
                }
            }
}

// ---------------- flash attention, swapped-QK^T, 8 waves x 32 q rows ----------------
// grid 256 blocks (1/CU): bid -> (bh, qblock) grouped so one bh's q-blocks share an XCD.
__global__ __launch_bounds__(512, 2) void attn_kernel(__hip_bfloat16* __restrict__ ws) {
    int bid = blockIdx.x;
    int g  = bid >> 6;          // bh / 8
    int qb = (bid >> 3) & 7;    // q block (0..7)
    int c  = bid & 7;           // bh % 8  -> XCD group
    int bh = g * 8 + c;

    int wave = threadIdx.x >> 6, lane = threadIdx.x & 63;
    int lg = lane >> 4, li = lane & 15;
    int qr0 = qb * 256 + wave * 32;

    const short* QT  = (const short*)(ws + OFF_QT) + (size_t)bh * N * 128;
    const char*  KTg = (const char*)((const short*)(ws + OFF_KT) + (size_t)bh * N * 128);
    const char*  VTg = (const char*)((const short*)(ws + OFF_VT) + (size_t)bh * DH * N);

    __shared__ __align__(16) short Ktile[2][64][128];   // 32 KB (2 buf)
    __shared__ __align__(16) short Vtile[2][64][64];    // 16 KB
    __shared__ __align__(16) short p_lds[8][32][72];    // 36 KB, per-wave P transpose

    // hoisted Q fragments (B-operand): qf[q2][kc]: Q[qr0+q2*16+li][kc*32+lg*8 ..]
    short8 qf[2][4];
#pragma unroll
    for (int q2 = 0; q2 < 2; ++q2)
#pragma unroll
        for (int kc = 0; kc < 4; ++kc)
            qf[q2][kc] = *(const short8*)(QT + (size_t)(qr0 + q2 * 16 + li) * 128 + kc * 32 + lg * 8);

    float m0 = -3e38f, m1 = -3e38f, l0 = 0.f, l1 = 0.f;
    f32x4 o[2][4] = {};
    char* pbase = (char*)&p_lds[wave][0][0];

    auto stage = [&](int t, int b) {
        int kv0 = t * 64;
        // K tile: 16 KB = 16 chunks of 1KB; wave handles 2
#pragma unroll
        for (int cc = 0; cc < 2; ++cc) {
            int ck = wave * 2 + cc;
            int a  = ck * 1024 + lane * 16;
            int r  = a >> 8;          // row in tile
            int cbx = a & 255;        // linear byte col
            gload16(KTg + (size_t)(kv0 + r) * 256 + (cbx ^ ((r & 7) << 4)),
                    (char*)&Ktile[b][0][0] + ck * 1024);
        }
        // V tile: 8 KB = 8 chunks; wave handles 1
        {
            int a  = wave * 1024 + lane * 16;
            int r  = a >> 7;          // d row
            int cbx = a & 127;
            gload16(VTg + (size_t)r * 4096 + kv0 * 2 + (cbx ^ ((r & 7) << 4)),
                    (char*)&Vtile[b][0][0] + wave * 1024);
        }
    };

    stage(0, 0);
    __syncthreads();
    int buf = 0;

    for (int t = 0; t < N / 64; ++t) {
        if (t + 1 < N / 64) stage(t + 1, buf ^ 1);
        const char* Kb = (const char*)&Ktile[buf][0][0];
        const char* Vb = (const char*)&Vtile[buf][0][0];

        // S^T = mfma(K, Q): lane holds S^T[k = cf*16+lg*4+j][q = li]
        f32x4 sT[2][4] = {};
#pragma unroll
        for (int cf = 0; cf < 4; ++cf) {
            int rr = cf * 16 + li;
            int sw = (rr & 7) << 4;
#pragma unroll
            for (int kc = 0; kc < 4; ++kc) {
                short8 kf = *(const short8*)(Kb + rr * 256 + ((kc * 64 + lg * 16) ^ sw));
                sT[0][cf] = __builtin_amdgcn_mfma_f32_16x16x32_bf16(kf, qf[0][kc], sT[0][cf], 0, 0, 0);
                sT[1][cf] = __builtin_amdgcn_mfma_f32_16x16x32_bf16(kf, qf[1][kc], sT[1][cf], 0, 0, 0);
            }
        }

        // lane-local tile max (q = li), then cross-lg reduce
        float pm0 = sT[0][0][0], pm1 = sT[1][0][0];
#pragma unroll
        for (int cf = 0; cf < 4; ++cf)
#pragma unroll
            for (int j = 0; j < 4; ++j) {
                pm0 = fmaxf(pm0, sT[0][cf][j]);
                pm1 = fmaxf(pm1, sT[1][cf][j]);
            }
        pm0 = fmaxf(pm0, __shfl_xor(pm0, 16)); pm0 = fmaxf(pm0, __shfl_xor(pm0, 32));
        pm1 = fmaxf(pm1, __shfl_xor(pm1, 16)); pm1 = fmaxf(pm1, __shfl_xor(pm1, 32));

        // defer-max (T13): only rescale when tile max grew past threshold
        float a0 = 1.f, a1 = 1.f;
        bool keep = __all((pm0 <= m0 + 8.f) && (pm1 <= m1 + 8.f));
        if (!keep) {
            float mn0 = fmaxf(m0, pm0), mn1 = fmaxf(m1, pm1);
            a0 = __expf(m0 - mn0); a1 = __expf(m1 - mn1);
#pragma unroll
            for (int j = 0; j < 4; ++j) {
                float aj0 = __shfl(a0, lg * 4 + j, 16);   // alpha in row space
                float aj1 = __shfl(a1, lg * 4 + j, 16);
#pragma unroll
                for (int vc = 0; vc < 4; ++vc) { o[0][vc][j] *= aj0; o[1][vc][j] *= aj1; }
            }
            m0 = mn0; m1 = mn1;
        }

        // exp, pack to bf16, store P^T -> P (A-layout) via per-wave LDS
        float ls0 = 0.f, ls1 = 0.f;
#pragma unroll
        for (int cf = 0; cf < 4; ++cf) {
            sv4 w0, w1;
#pragma unroll
            for (int j = 0; j < 4; ++j) {
                float p0 = __expf(sT[0][cf][j] - m0); ls0 += p0; w0[j] = f2b(p0);
                float p1 = __expf(sT[1][cf][j] - m1); ls1 += p1; w1[j] = f2b(p1);
            }
            *(sv4*)(pbase + (size_t)li * 144 + cf * 32 + lg * 8) = w0;
            *(sv4*)(pbase + (size_t)(16 + li) * 144 + cf * 32 + lg * 8) = w1;
        }
        ls0 += __shfl_xor(ls0, 16); ls0 += __shfl_xor(ls0, 32);
        ls1 += __shfl_xor(ls1, 16); ls1 += __shfl_xor(ls1, 32);
        l0 = l0 * a0 + ls0;
        l1 = l1 * a1 + ls1;

        // P fragments (A-operand): row q = li, k = ks*32 + lg*8
        short8 pf0a = *(const short8*)(pbase + (size_t)li * 144 + lg * 16);
        short8 pf0b = *(const short8*)(pbase + (size_t)li * 144 + 64 + lg * 16);
        short8 pf1a = *(const short8*)(pbase + (size_t)(16 + li) * 144 + lg * 16);
        short8 pf1b = *(const short8*)(pbase + (size_t)(16 + li) * 144 + 64 + lg * 16);

        // PV: o[q2][vc] += P * V^T
#pragma unroll
        for (int vc = 0; vc < 4; ++vc) {
            int dv = vc * 16 + li;
            int sw = (dv & 7) << 4;
            short8 v0 = *(const short8*)(Vb + dv * 128 + ((lg * 16) ^ sw));
            short8 v1 = *(const short8*)(Vb + dv * 128 + ((64 + lg * 16) ^ sw));
            o[0][vc] = __builtin_amdgcn_mfma_f32_16x16x32_bf16(pf0a, v0, o[0][vc], 0, 0, 0);
            o[0][vc] = __builtin_amdgcn_mfma_f32_16x16x32_bf16(pf0b, v1, o[0][vc], 0, 0, 0);
            o[1][vc] = __builtin_amdgcn_mfma_f32_16x16x32_bf16(pf1a, v0, o[1][vc], 0, 0, 0);
            o[1][vc] = __builtin_amdgcn_mfma_f32_16x16x32_bf16(pf1b, v1, o[1][vc], 0, 0, 0);
        }

        __syncthreads();
        buf ^= 1;
    }

    __hip_bfloat16* AO = ws + OFF_AO;
    int b = bh >> 3, h = bh & 7;
#pragma unroll
    for (int q2 = 0; q2 < 2; ++q2) {
        float lq = q2 ? l1 : l0;
#pragma unroll
        for (int j = 0; j < 4; ++j) {
            float lv = __shfl(lq, lg * 4 + j, 16);
            float inv = 1.f / lv;
            int nrow = qr0 + q2 * 16 + lg * 4 + j;
#pragma unroll
            for (int vc = 0; vc < 4; ++vc)
                AO[(size_t)(b * N + nrow) * INNER + h * 64 + vc * 16 + li] =
                    __float2bfloat16(o[q2][vc][j] * inv);
        }
    }
}

// ---------------- GEMM3: out = AO @ w_out + b_out (f32 out) ----------------
__global__ __launch_bounds__(256) void gemm_out(const __hip_bfloat16* __restrict__ ws_c,
                                                const float* __restrict__ bout,
                                                float* __restrict__ out) {
    const __hip_bfloat16* AO = ws_c + OFF_AO;
    const __hip_bfloat16* Bt = ws_c + OFF_WOUTT;
    int m0 = blockIdx.x * 128, n0 = blockIdx.y * 128;

    __shared__ __align__(16) short As[128][72];
    __shared__ __align__(16) short Bs[128][72];

    int tid  = threadIdx.x;
    int wave = tid >> 6, lane = tid & 63;
    int wrow = wave >> 1, wcol = wave & 1;
    int lg = lane >> 4, li = lane & 15;

    f32x4 acc[4][4] = {};

    for (int k0 = 0; k0 < 512; k0 += 64) {
#pragma unroll
        for (int r = 0; r < 4; ++r) {
            int idx = (tid + r * 256) * 8;
            int row = idx >> 6, kk = idx & 63;
            *(short8*)(&As[row][kk]) = *(const short8*)(AO + (size_t)(m0 + row) * 512 + k0 + kk);
            *(short8*)(&Bs[row][kk]) = *(const short8*)(Bt + (size_t)(n0 + row) * 512 + k0 + kk);
        }
        __syncthreads();
#pragma unroll
        for (int ks = 0; ks < 2; ++ks) {
            short8 af[4], bf[4];
#pragma unroll
            for (int m = 0; m < 4; ++m)
                af[m] = *(const short8*)(&As[wrow * 64 + m * 16 + li][ks * 32 + lg * 8]);
#pragma unroll
            for (int n = 0; n < 4; ++n)
                bf[n] = *(const short8*)(&Bs[wcol * 64 + n * 16 + li][ks * 32 + lg * 8]);
#pragma unroll
            for (int m = 0; m < 4; ++m)
#pragma unroll
                for (int n = 0; n < 4; ++n)
                    acc[m][n] = __builtin_amdgcn_mfma_f32_16x16x32_bf16(af[m], bf[n], acc[m][n], 0, 0, 0);
        }
        __syncthreads();
    }
#pragma unroll
    for (int m = 0; m < 4; ++m)
#pragma unroll
        for (int n = 0; n < 4; ++n)
#pragma unroll
            for (int j = 0; j < 4; ++j) {
                int row = m0 + wrow * 64 + m * 16 + lg * 4 + j;
                int col = n0 + wcol * 64 + n * 16 + li;
                out[(size_t)row * 512 + col] = acc[m][n][j] + bout[col];
            }
}

extern "C" void kernel_launch(void* const* d_in, const int* in_sizes, int n_in,
                              void* d_out, int out_size, void* d_ws, size_t ws_size,
                              hipStream_t stream) {
    const float* x    = (const float*)d_in[0];
    const float* bias = (const float*)d_in[1];
    const float* wqkv = (const float*)d_in[2];
    const float* wout = (const float*)d_in[3];
    const float* bout = (const float*)d_in[4];
    float* out = (float*)d_out;
    __hip_bfloat16* ws = (__hip_bfloat16*)d_ws;

    hipLaunchKernelGGL(prep_kernel, dim3(512), dim3(256), 0, stream, wqkv, wout, ws);
    hipLaunchKernelGGL(gemm_qkv, dim3(64, 20), dim3(256), 0, stream, x, bias, ws);
    hipLaunchKernelGGL(attn_kernel, dim3(256), dim3(512), 0, stream, ws);
    hipLaunchKernelGGL(gemm_out, dim3(64, 4), dim3(256), 0, stream, (const __hip_bfloat16*)ws, bout, out);
}

// Round 3
// 144.956 us; speedup vs baseline: 2.8897x; 1.0527x over previous
//
#include <hip/hip_runtime.h>
#include <hip/hip_bf16.h>

#define DEV __device__ __forceinline__

typedef __attribute__((ext_vector_type(8))) short short8;
typedef __attribute__((ext_vector_type(4))) int i32x4;
typedef __attribute__((ext_vector_type(2))) int i32x2;
typedef __attribute__((ext_vector_type(4))) float f32x4;
typedef __attribute__((ext_vector_type(16))) float f32x16;

constexpr int B = 4, N = 2048, H = 8, DH = 64;
constexpr int INNER = H * DH;          // 512
constexpr int BH = B * H;              // 32
constexpr float SCALE = 0.125f;        // DH^-0.5

// ---- workspace layout (bf16 elements) ----
constexpr size_t OFF_WQKVT = 0;                               // [1536][512]
constexpr size_t OFF_WOUTT = OFF_WQKVT + (size_t)1536 * 512;  // [512][512]
constexpr size_t OFF_QT    = OFF_WOUTT + (size_t)512 * 512;   // [32][2048][128]
constexpr size_t OFF_KT    = OFF_QT + (size_t)BH * N * 128;   // [32][2048][128]
constexpr size_t OFF_VT    = OFF_KT + (size_t)BH * N * 128;   // [32][64][2048]
constexpr size_t OFF_AO    = OFF_VT + (size_t)BH * DH * N;    // [8192][512]
constexpr size_t OFF_XBF   = OFF_AO + (size_t)8192 * 512;     // [8192][512] x as bf16
constexpr size_t OFF_BBF   = OFF_AO;                          // bias bf16 (aliases AO; AO written later)

DEV short f2b(float f) {
    __hip_bfloat16 h = __float2bfloat16(f);
    return __builtin_bit_cast(short, h);
}

DEV int cvtpk(float lo, float hi) {
    int r;
    asm("v_cvt_pk_bf16_f32 %0, %1, %2" : "=v"(r) : "v"(lo), "v"(hi));
    return r;
}

DEV void plswap(int& a, int& b) {
    i32x2 r = __builtin_amdgcn_permlane32_swap(a, b, false, false);
    a = r.x; b = r.y;
}

DEV void gload16(const void* g, void* l) {
    __builtin_amdgcn_global_load_lds(
        (const __attribute__((address_space(1))) unsigned int*)g,
        (__attribute__((address_space(3))) unsigned int*)l, 16, 0, 0);
}

// ---------------- prep: weight transpose + x/bias -> bf16 ----------------
__global__ void prep_kernel(const float* __restrict__ wqkv,
                            const float* __restrict__ wout,
                            const float* __restrict__ x,
                            const float* __restrict__ bias,
                            __hip_bfloat16* __restrict__ ws) {
    __hip_bfloat16* wqkvT = ws + OFF_WQKVT;
    __hip_bfloat16* woutT = ws + OFF_WOUTT;
    short8* xbf = (short8*)(ws + OFF_XBF);
    short8* bbf = (short8*)(ws + OFF_BBF);
    int tid = blockIdx.x * blockDim.x + threadIdx.x;
    const int nconv = 8192 * 512 / 8;         // short8 items per conversion
    const int t1 = 512 * 1536 / 4;            // wqkv float4s
    const int t2 = 512 * 512 / 4;             // wout float4s
    const int total = 2 * nconv + t1 + t2;
    for (int i = tid; i < total; i += gridDim.x * blockDim.x) {
        if (i < 2 * nconv) {
            const float4* src = (const float4*)(i < nconv ? x : bias);
            short8* dst = i < nconv ? xbf : bbf;
            int j = i < nconv ? i : i - nconv;
            float4 v0 = src[2 * j], v1 = src[2 * j + 1];
            short8 sv;
            sv[0] = f2b(v0.x); sv[1] = f2b(v0.y); sv[2] = f2b(v0.z); sv[3] = f2b(v0.w);
            sv[4] = f2b(v1.x); sv[5] = f2b(v1.y); sv[6] = f2b(v1.z); sv[7] = f2b(v1.w);
            dst[j] = sv;
        } else if (i < 2 * nconv + t1) {
            int j = i - 2 * nconv;
            int k  = j / 384;
            int c4 = (j % 384) * 4;
            float4 v = ((const float4*)wqkv)[j];
            wqkvT[(size_t)(c4 + 0) * 512 + k] = __float2bfloat16(v.x);
            wqkvT[(size_t)(c4 + 1) * 512 + k] = __float2bfloat16(v.y);
            wqkvT[(size_t)(c4 + 2) * 512 + k] = __float2bfloat16(v.z);
            wqkvT[(size_t)(c4 + 3) * 512 + k] = __float2bfloat16(v.w);
        } else {
            int j = i - 2 * nconv - t1;
            int k  = j / 128;
            int c4 = (j % 128) * 4;
            float4 v = ((const float4*)wout)[j];
            woutT[(size_t)(c4 + 0) * 512 + k] = __float2bfloat16(v.x);
            woutT[(size_t)(c4 + 1) * 512 + k] = __float2bfloat16(v.y);
            woutT[(size_t)(c4 + 2) * 512 + k] = __float2bfloat16(v.z);
            woutT[(size_t)(c4 + 3) * 512 + k] = __float2bfloat16(v.w);
        }
    }
}

// ---------------- GEMM1: qkv = {x,bias}@w_qkv -> QT/KT/VT (m97-style gload_lds) ----------------
__global__ __launch_bounds__(256) void gemm_qkv(__hip_bfloat16* __restrict__ ws) {
    int mt = blockIdx.x, yt = blockIdx.y;
    bool src_is_bias = (yt >= 12);
    int nt = src_is_bias ? yt - 12 : yt;
    const short* A  = (const short*)(ws + (src_is_bias ? OFF_BBF : OFF_XBF));
    const short* Bt = (const short*)(ws + OFF_WQKVT);
    int m0 = mt * 128, n0 = nt * 128;

    __shared__ __align__(16) short As[128][64];
    __shared__ __align__(16) short Bs[128][64];

    int tid  = threadIdx.x;
    int wave = tid >> 6, lane = tid & 63;
    int wrow = wave >> 1, wcol = wave & 1;
    int lg = lane >> 4, li = lane & 15;

    f32x4 acc[4][4] = {};

    for (int k0 = 0; k0 < 512; k0 += 64) {
#pragma unroll
        for (int i = 0; i < 4; ++i) {
            int c = wave * 4 + i;
            int r = c * 8 + (lane >> 3);
            gload16((const char*)A + ((size_t)(m0 + r) * 512 + k0 + (lane & 7) * 8) * 2,
                    (char*)&As[0][0] + c * 1024);
            gload16((const char*)Bt + ((size_t)(n0 + r) * 512 + k0 + (lane & 7) * 8) * 2,
                    (char*)&Bs[0][0] + c * 1024);
        }
        __syncthreads();
#pragma unroll
        for (int ks = 0; ks < 2; ++ks) {
            short8 af[4], bf[4];
#pragma unroll
            for (int m = 0; m < 4; ++m)
                af[m] = *(const short8*)(&As[wrow * 64 + m * 16 + li][ks * 32 + lg * 8]);
#pragma unroll
            for (int n = 0; n < 4; ++n)
                bf[n] = *(const short8*)(&Bs[wcol * 64 + n * 16 + li][ks * 32 + lg * 8]);
#pragma unroll
            for (int m = 0; m < 4; ++m)
#pragma unroll
                for (int n = 0; n < 4; ++n)
                    acc[m][n] = __builtin_amdgcn_mfma_f32_16x16x32_bf16(af[m], bf[n], acc[m][n], 0, 0, 0);
        }
        __syncthreads();
    }

    __hip_bfloat16* QT = ws + OFF_QT;
    __hip_bfloat16* KT = ws + OFF_KT;
    __hip_bfloat16* VT = ws + OFF_VT;
    int qkoff = src_is_bias ? 64 : 0;
#pragma unroll
    for (int m = 0; m < 4; ++m)
#pragma unroll
        for (int n = 0; n < 4; ++n)
#pragma unroll
            for (int j = 0; j < 4; ++j) {
                int row = m0 + wrow * 64 + m * 16 + lg * 4 + j;
                int col = n0 + wcol * 64 + n * 16 + li;
                float v = acc[m][n][j];
                int b = row >> 11, nn = row & 2047;
                if (col < 512) {
                    int h = col >> 6, d = col & 63;
                    QT[((size_t)(b * H + h) * N + nn) * 128 + d + qkoff] = __float2bfloat16(v * SCALE);
                } else if (col < 1024) {
                    int c = col - 512; int h = c >> 6, d = c & 63;
                    KT[((size_t)(b * H + h) * N + nn) * 128 + d + qkoff] = __float2bfloat16(v);
                } else {
                    int c = col - 1024; int h = c >> 6, d = c & 63;
                    VT[((size_t)(b * H + h) * DH + d) * N + nn] = __float2bfloat16(v);
                }
            }
}

// ---------------- flash attention: 32x32 MFMA, in-register softmax (T12) ----------------
// grid 512 = 8 XCD-groups x 4 bh x 16 qblocks; 4 waves x 32 q each.
__global__ __launch_bounds__(256, 3) void attn_kernel(__hip_bfloat16* __restrict__ ws) {
    int bid = blockIdx.x;
    int c   = bid & 7;
    int idx = bid >> 3;
    int bh  = (idx & 3) * 8 + c;      // 4 bh per XCD -> K/V L2-resident
    int qb  = idx >> 2;

    int wave = threadIdx.x >> 6, lane = threadIdx.x & 63;
    int li32 = lane & 31, hi = lane >> 5;
    int qr0 = qb * 128 + wave * 32;

    const short* QT  = (const short*)(ws + OFF_QT) + (size_t)bh * N * 128;
    const char*  KTg = (const char*)((const short*)(ws + OFF_KT) + (size_t)bh * N * 128);
    const char*  VTg = (const char*)((const short*)(ws + OFF_VT) + (size_t)bh * DH * N);

    __shared__ __align__(16) short Ktile[2][64][128];   // 32 KB dbuf
    __shared__ __align__(16) short Vtile[2][64][64];    // 16 KB dbuf

    // Q B-fragments in registers: qf[kc]: Q^T[d = kc*16 + hi*8 + e][q = li32]
    short8 qf[8];
#pragma unroll
    for (int kc = 0; kc < 8; ++kc)
        qf[kc] = *(const short8*)(QT + (size_t)(qr0 + li32) * 128 + kc * 16 + hi * 8);

    float m_run = -3e38f, l_run = 0.f;
    f32x16 o[2] = {};

    auto stage = [&](int t, int b) {
        int kv0 = t * 64;
#pragma unroll
        for (int cc = 0; cc < 4; ++cc) {          // K: 16 KB, 4 chunks/wave
            int ck = wave * 4 + cc;
            int r  = ck * 4 + (lane >> 4);
            int cbx = (lane & 15) * 16;
            gload16(KTg + (size_t)(kv0 + r) * 256 + (cbx ^ ((r & 7) << 4)),
                    (char*)&Ktile[b][0][0] + ck * 1024);
        }
#pragma unroll
        for (int cc = 0; cc < 2; ++cc) {          // V: 8 KB, 2 chunks/wave
            int ck = wave * 2 + cc;
            int r  = ck * 8 + (lane >> 3);
            int cbx = (lane & 7) * 16;
            gload16(VTg + (size_t)r * 4096 + kv0 * 2 + (cbx ^ ((r & 7) << 4)),
                    (char*)&Vtile[b][0][0] + ck * 1024);
        }
    };

    stage(0, 0);
    __syncthreads();
    int buf = 0;

    for (int t = 0; t < N / 64; ++t) {
        if (t + 1 < N / 64) stage(t + 1, buf ^ 1);
        const char* Kb = (const char*)&Ktile[buf][0][0];
        const char* Vb = (const char*)&Vtile[buf][0][0];

        // S^T[kv][q]: sT[sub], kv = sub*32 + (r&3)+8*(r>>2)+4*hi, q = li32
        f32x16 sT[2] = {};
        __builtin_amdgcn_s_setprio(1);
#pragma unroll
        for (int sub = 0; sub < 2; ++sub) {
            int row = sub * 32 + li32;
            int sw  = (row & 7) << 4;
            const char* kbase = Kb + row * 256;
#pragma unroll
            for (int kc = 0; kc < 8; ++kc) {
                short8 kf = *(const short8*)(kbase + ((kc * 32 + hi * 16) ^ sw));
                sT[sub] = __builtin_amdgcn_mfma_f32_32x32x16_bf16(kf, qf[kc], sT[sub], 0, 0, 0);
            }
        }
        __builtin_amdgcn_s_setprio(0);

        // tile max (per q = li32)
        float pm = sT[0][0];
#pragma unroll
        for (int sub = 0; sub < 2; ++sub)
#pragma unroll
            for (int r = 0; r < 16; ++r) pm = fmaxf(pm, sT[sub][r]);
        pm = fmaxf(pm, __shfl_xor(pm, 32));

        // defer-max (T13, THR=8)
        if (__any(pm > m_run + 8.f)) {
            float mn = fmaxf(m_run, pm);
            float al = __expf(m_run - mn);
#pragma unroll
            for (int a = 0; a < 2; ++a)
#pragma unroll
                for (int r = 0; r < 16; ++r) o[a][r] *= al;
            l_run *= al;
            m_run = mn;
        }

        // exp + pack to bf16 words
        float ls = 0.f;
        int w[2][8];
#pragma unroll
        for (int sub = 0; sub < 2; ++sub)
#pragma unroll
            for (int r2 = 0; r2 < 8; ++r2) {
                float p0 = __expf(sT[sub][2 * r2]     - m_run);
                float p1 = __expf(sT[sub][2 * r2 + 1] - m_run);
                ls += p0 + p1;
                w[sub][r2] = cvtpk(p0, p1);
            }
        ls += __shfl_xor(ls, 32);
        l_run += ls;

        // P^T B-fragments via permlane32_swap (T12)
        short8 pf[2][2];
#pragma unroll
        for (int sub = 0; sub < 2; ++sub) {
            plswap(w[sub][0], w[sub][2]); plswap(w[sub][1], w[sub][3]);
            plswap(w[sub][4], w[sub][6]); plswap(w[sub][5], w[sub][7]);
            i32x4 f0 = { w[sub][0], w[sub][1], w[sub][2], w[sub][3] };
            i32x4 f1 = { w[sub][4], w[sub][5], w[sub][6], w[sub][7] };
            pf[sub][0] = __builtin_bit_cast(short8, f0);
            pf[sub][1] = __builtin_bit_cast(short8, f1);
        }

        // PV: O^T[dv][q] += V^T[dv][kv] * P^T[kv][q]
        __builtin_amdgcn_s_setprio(1);
#pragma unroll
        for (int sub = 0; sub < 2; ++sub)
#pragma unroll
            for (int ksel = 0; ksel < 2; ++ksel) {
                int cc = sub * 2 + ksel;
#pragma unroll
                for (int a = 0; a < 2; ++a) {
                    int row = a * 32 + li32;
                    int sw  = (row & 7) << 4;
                    short8 vf = *(const short8*)(Vb + row * 128 + ((cc * 32 + hi * 16) ^ sw));
                    o[a] = __builtin_amdgcn_mfma_f32_32x32x16_bf16(vf, pf[sub][ksel], o[a], 0, 0, 0);
                }
            }
        __builtin_amdgcn_s_setprio(0);

        __syncthreads();
        buf ^= 1;
    }

    // epilogue: O^T -> LDS transpose -> coalesced AO rows
    __hip_bfloat16* AO = ws + OFF_AO;
    int b = bh >> 3, h = bh & 7;
    char* tb = (char*)&Ktile[0][0][0] + wave * 4096;
    float inv = 1.f / l_run;
#pragma unroll
    for (int a = 0; a < 2; ++a)
#pragma unroll
        for (int r2 = 0; r2 < 8; ++r2) {
            int r = 2 * r2;
            int dv = (r & 3) + 8 * (r >> 2) + 4 * hi + 32 * a;
            int word = cvtpk(o[a][r] * inv, o[a][r + 1] * inv);
            *(int*)(tb + li32 * 128 + ((dv * 2) ^ ((li32 & 7) << 4))) = word;
        }
#pragma unroll
    for (int qq = 0; qq < 32; qq += 8) {
        int q = qq + (lane >> 3), seg = lane & 7;
        short8 vrow = *(const short8*)(tb + q * 128 + ((seg * 16) ^ ((q & 7) << 4)));
        *(short8*)(AO + (size_t)(b * N + qr0 + q) * INNER + h * 64 + seg * 8) = vrow;
    }
}

// ---------------- GEMM3: out = AO @ w_out + b_out (m97-style gload_lds) ----------------
__global__ __launch_bounds__(256) void gemm_out(const __hip_bfloat16* __restrict__ ws_c,
                                                const float* __restrict__ bout,
                                                float* __restrict__ out) {
    const short* AO = (const short*)(ws_c + OFF_AO);
    const short* Bt = (const short*)(ws_c + OFF_WOUTT);
    int m0 = blockIdx.x * 128, n0 = blockIdx.y * 128;

    __shared__ __align__(16) short As[128][64];
    __shared__ __align__(16) short Bs[128][64];

    int tid  = threadIdx.x;
    int wave = tid >> 6, lane = tid & 63;
    int wrow = wave >> 1, wcol = wave & 1;
    int lg = lane >> 4, li = lane & 15;

    f32x4 acc[4][4] = {};

    for (int k0 = 0; k0 < 512; k0 += 64) {
#pragma unroll
        for (int i = 0; i < 4; ++i) {
            int c = wave * 4 + i;
            int r = c * 8 + (lane >> 3);
            gload16((const char*)AO + ((size_t)(m0 + r) * 512 + k0 + (lane & 7) * 8) * 2,
                    (char*)&As[0][0] + c * 1024);
            gload16((const char*)Bt + ((size_t)(n0 + r) * 512 + k0 + (lane & 7) * 8) * 2,
                    (char*)&Bs[0][0] + c * 1024);
        }
        __syncthreads();
#pragma unroll
        for (int ks = 0; ks < 2; ++ks) {
            short8 af[4], bf[4];
#pragma unroll
            for (int m = 0; m < 4; ++m)
                af[m] = *(const short8*)(&As[wrow * 64 + m * 16 + li][ks * 32 + lg * 8]);
#pragma unroll
            for (int n = 0; n < 4; ++n)
                bf[n] = *(const short8*)(&Bs[wcol * 64 + n * 16 + li][ks * 32 + lg * 8]);
#pragma unroll
            for (int m = 0; m < 4; ++m)
#pragma unroll
                for (int n = 0; n < 4; ++n)
                    acc[m][n] = __builtin_amdgcn_mfma_f32_16x16x32_bf16(af[m], bf[n], acc[m][n], 0, 0, 0);
        }
        __syncthreads();
    }
#pragma unroll
    for (int m = 0; m < 4; ++m)
#pragma unroll
        for (int n = 0; n < 4; ++n)
#pragma unroll
            for (int j = 0; j < 4; ++j) {
                int row = m0 + wrow * 64 + m * 16 + lg * 4 + j;
                int col = n0 + wcol * 64 + n * 16 + li;
                out[(size_t)row * 512 + col] = acc[m][n][j] + bout[col];
            }
}

extern "C" void kernel_launch(void* const* d_in, const int* in_sizes, int n_in,
                              void* d_out, int out_size, void* d_ws, size_t ws_size,
                              hipStream_t stream) {
    const float* x    = (const float*)d_in[0];
    const float* bias = (const float*)d_in[1];
    const float* wqkv = (const float*)d_in[2];
    const float* wout = (const float*)d_in[3];
    const float* bout = (const float*)d_in[4];
    float* out = (float*)d_out;
    __hip_bfloat16* ws = (__hip_bfloat16*)d_ws;

    hipLaunchKernelGGL(prep_kernel, dim3(2048), dim3(256), 0, stream, wqkv, wout, x, bias, ws);
    hipLaunchKernelGGL(gemm_qkv, dim3(64, 20), dim3(256), 0, stream, ws);
    hipLaunchKernelGGL(attn_kernel, dim3(512), dim3(256), 0, stream, ws);
    hipLaunchKernelGGL(gemm_out, dim3(64, 4), dim3(256), 0, stream, (const __hip_bfloat16*)ws, bout, out);
}

// Round 4
// 144.909 us; speedup vs baseline: 2.8907x; 1.0003x over previous
//
#include <hip/hip_runtime.h>
#include <hip/hip_bf16.h>

#define DEV __device__ __forceinline__

typedef __attribute__((ext_vector_type(8))) short short8;
typedef __attribute__((ext_vector_type(4))) int i32x4;
typedef __attribute__((ext_vector_type(2))) int i32x2;
typedef __attribute__((ext_vector_type(4))) float f32x4;
typedef __attribute__((ext_vector_type(16))) float f32x16;

constexpr int B = 4, N = 2048, H = 8, DH = 64;
constexpr int INNER = H * DH;          // 512
constexpr int BH = B * H;              // 32
// SCALE * log2(e): QK^T then yields log2-domain scores -> v_exp_f32 (2^x) directly
constexpr float QSCALE = 0.125f * 1.44269504088896f;

// ---- workspace layout (bf16 elements) ----
constexpr size_t OFF_WQKVT = 0;                               // [1536][512]
constexpr size_t OFF_WOUTT = OFF_WQKVT + (size_t)1536 * 512;  // [512][512]
constexpr size_t OFF_QT    = OFF_WOUTT + (size_t)512 * 512;   // [32][2048][128]
constexpr size_t OFF_KT    = OFF_QT + (size_t)BH * N * 128;   // [32][2048][128]
constexpr size_t OFF_VT    = OFF_KT + (size_t)BH * N * 128;   // [32][64][2048]
constexpr size_t OFF_AO    = OFF_VT + (size_t)BH * DH * N;    // [8192][512]
constexpr size_t OFF_XBF   = OFF_AO + (size_t)8192 * 512;     // [8192][512] x as bf16
constexpr size_t OFF_BBF   = OFF_AO;                          // bias bf16 (aliases AO; AO written later)

DEV short f2b(float f) {
    __hip_bfloat16 h = __float2bfloat16(f);
    return __builtin_bit_cast(short, h);
}

DEV int cvtpk(float lo, float hi) {
    int r;
    asm("v_cvt_pk_bf16_f32 %0, %1, %2" : "=v"(r) : "v"(lo), "v"(hi));
    return r;
}

DEV float fexp2(float x) {
    float r;
    asm("v_exp_f32 %0, %1" : "=v"(r) : "v"(x));
    return r;
}

DEV void plswap(int& a, int& b) {
    i32x2 r = __builtin_amdgcn_permlane32_swap(a, b, false, false);
    a = r.x; b = r.y;
}

DEV void gload16(const void* g, void* l) {
    __builtin_amdgcn_global_load_lds(
        (const __attribute__((address_space(1))) unsigned int*)g,
        (__attribute__((address_space(3))) unsigned int*)l, 16, 0, 0);
}

// ---------------- prep: weight transpose + x/bias -> bf16 ----------------
__global__ void prep_kernel(const float* __restrict__ wqkv,
                            const float* __restrict__ wout,
                            const float* __restrict__ x,
                            const float* __restrict__ bias,
                            __hip_bfloat16* __restrict__ ws) {
    __hip_bfloat16* wqkvT = ws + OFF_WQKVT;
    __hip_bfloat16* woutT = ws + OFF_WOUTT;
    short8* xbf = (short8*)(ws + OFF_XBF);
    short8* bbf = (short8*)(ws + OFF_BBF);
    int tid = blockIdx.x * blockDim.x + threadIdx.x;
    const int nconv = 8192 * 512 / 8;
    const int t1 = 512 * 1536 / 4;
    const int t2 = 512 * 512 / 4;
    const int total = 2 * nconv + t1 + t2;
    for (int i = tid; i < total; i += gridDim.x * blockDim.x) {
        if (i < 2 * nconv) {
            const float4* src = (const float4*)(i < nconv ? x : bias);
            short8* dst = i < nconv ? xbf : bbf;
            int j = i < nconv ? i : i - nconv;
            float4 v0 = src[2 * j], v1 = src[2 * j + 1];
            short8 sv;
            sv[0] = f2b(v0.x); sv[1] = f2b(v0.y); sv[2] = f2b(v0.z); sv[3] = f2b(v0.w);
            sv[4] = f2b(v1.x); sv[5] = f2b(v1.y); sv[6] = f2b(v1.z); sv[7] = f2b(v1.w);
            dst[j] = sv;
        } else if (i < 2 * nconv + t1) {
            int j = i - 2 * nconv;
            int k  = j / 384;
            int c4 = (j % 384) * 4;
            float4 v = ((const float4*)wqkv)[j];
            wqkvT[(size_t)(c4 + 0) * 512 + k] = __float2bfloat16(v.x);
            wqkvT[(size_t)(c4 + 1) * 512 + k] = __float2bfloat16(v.y);
            wqkvT[(size_t)(c4 + 2) * 512 + k] = __float2bfloat16(v.z);
            wqkvT[(size_t)(c4 + 3) * 512 + k] = __float2bfloat16(v.w);
        } else {
            int j = i - 2 * nconv - t1;
            int k  = j / 128;
            int c4 = (j % 128) * 4;
            float4 v = ((const float4*)wout)[j];
            woutT[(size_t)(c4 + 0) * 512 + k] = __float2bfloat16(v.x);
            woutT[(size_t)(c4 + 1) * 512 + k] = __float2bfloat16(v.y);
            woutT[(size_t)(c4 + 2) * 512 + k] = __float2bfloat16(v.z);
            woutT[(size_t)(c4 + 3) * 512 + k] = __float2bfloat16(v.w);
        }
    }
}

// ---------------- GEMM1: qkv = {x,bias}@w_qkv -> QT/KT/VT ----------------
__global__ __launch_bounds__(256) void gemm_qkv(__hip_bfloat16* __restrict__ ws) {
    int mt = blockIdx.x, yt = blockIdx.y;
    bool src_is_bias = (yt >= 12);
    int nt = src_is_bias ? yt - 12 : yt;
    const short* A  = (const short*)(ws + (src_is_bias ? OFF_BBF : OFF_XBF));
    const short* Bt = (const short*)(ws + OFF_WQKVT);
    int m0 = mt * 128, n0 = nt * 128;

    __shared__ __align__(16) short As[128][64];
    __shared__ __align__(16) short Bs[128][64];

    int tid  = threadIdx.x;
    int wave = tid >> 6, lane = tid & 63;
    int wrow = wave >> 1, wcol = wave & 1;
    int lg = lane >> 4, li = lane & 15;

    f32x4 acc[4][4] = {};

    for (int k0 = 0; k0 < 512; k0 += 64) {
#pragma unroll
        for (int i = 0; i < 4; ++i) {
            int c = wave * 4 + i;
            int r = c * 8 + (lane >> 3);
            gload16((const char*)A + ((size_t)(m0 + r) * 512 + k0 + (lane & 7) * 8) * 2,
                    (char*)&As[0][0] + c * 1024);
            gload16((const char*)Bt + ((size_t)(n0 + r) * 512 + k0 + (lane & 7) * 8) * 2,
                    (char*)&Bs[0][0] + c * 1024);
        }
        __syncthreads();
#pragma unroll
        for (int ks = 0; ks < 2; ++ks) {
            short8 af[4], bf[4];
#pragma unroll
            for (int m = 0; m < 4; ++m)
                af[m] = *(const short8*)(&As[wrow * 64 + m * 16 + li][ks * 32 + lg * 8]);
#pragma unroll
            for (int n = 0; n < 4; ++n)
                bf[n] = *(const short8*)(&Bs[wcol * 64 + n * 16 + li][ks * 32 + lg * 8]);
#pragma unroll
            for (int m = 0; m < 4; ++m)
#pragma unroll
                for (int n = 0; n < 4; ++n)
                    acc[m][n] = __builtin_amdgcn_mfma_f32_16x16x32_bf16(af[m], bf[n], acc[m][n], 0, 0, 0);
        }
        __syncthreads();
    }

    __hip_bfloat16* QT = ws + OFF_QT;
    __hip_bfloat16* KT = ws + OFF_KT;
    __hip_bfloat16* VT = ws + OFF_VT;
    int qkoff = src_is_bias ? 64 : 0;
#pragma unroll
    for (int m = 0; m < 4; ++m)
#pragma unroll
        for (int n = 0; n < 4; ++n)
#pragma unroll
            for (int j = 0; j < 4; ++j) {
                int row = m0 + wrow * 64 + m * 16 + lg * 4 + j;
                int col = n0 + wcol * 64 + n * 16 + li;
                float v = acc[m][n][j];
                int b = row >> 11, nn = row & 2047;
                if (col < 512) {
                    int h = col >> 6, d = col & 63;
                    QT[((size_t)(b * H + h) * N + nn) * 128 + d + qkoff] = __float2bfloat16(v * QSCALE);
                } else if (col < 1024) {
                    int c = col - 512; int h = c >> 6, d = c & 63;
                    KT[((size_t)(b * H + h) * N + nn) * 128 + d + qkoff] = __float2bfloat16(v);
                } else {
                    int c = col - 1024; int h = c >> 6, d = c & 63;
                    VT[((size_t)(b * H + h) * DH + d) * N + nn] = __float2bfloat16(v);
                }
            }
}

// ---------------- flash attention: 32x32 MFMA, in-reg softmax, dual-tile pipeline ----------------
__global__ __launch_bounds__(256, 2) void attn_kernel(__hip_bfloat16* __restrict__ ws) {
    int bid = blockIdx.x;
    int c   = bid & 7;
    int idx = bid >> 3;
    int bh  = (idx & 3) * 8 + c;      // 4 bh per XCD -> K/V L2-resident
    int qb  = idx >> 2;

    int wave = threadIdx.x >> 6, lane = threadIdx.x & 63;
    int li32 = lane & 31, hi = lane >> 5;
    int qr0 = qb * 128 + wave * 32;

    const short* QT  = (const short*)(ws + OFF_QT) + (size_t)bh * N * 128;
    const char*  KTg = (const char*)((const short*)(ws + OFF_KT) + (size_t)bh * N * 128);
    const char*  VTg = (const char*)((const short*)(ws + OFF_VT) + (size_t)bh * DH * N);

    __shared__ __align__(16) short Ktile[2][64][128];   // 32 KB dbuf
    __shared__ __align__(16) short Vtile[2][64][64];    // 16 KB dbuf

    short8 qf[8];
#pragma unroll
    for (int kc = 0; kc < 8; ++kc)
        qf[kc] = *(const short8*)(QT + (size_t)(qr0 + li32) * 128 + kc * 16 + hi * 8);

    float m_run = -3e38f, l_run = 0.f;
    f32x16 o[2] = {};

    auto stageK = [&](int t, int b) {
        int kv0 = t * 64;
#pragma unroll
        for (int cc = 0; cc < 4; ++cc) {
            int ck = wave * 4 + cc;
            int r  = ck * 4 + (lane >> 4);
            int cbx = (lane & 15) * 16;
            gload16(KTg + (size_t)(kv0 + r) * 256 + (cbx ^ ((r & 7) << 4)),
                    (char*)&Ktile[b][0][0] + ck * 1024);
        }
    };
    auto stageV = [&](int t, int b) {
        int kv0 = t * 64;
#pragma unroll
        for (int cc = 0; cc < 2; ++cc) {
            int ck = wave * 2 + cc;
            int r  = ck * 8 + (lane >> 3);
            int cbx = (lane & 7) * 16;
            gload16(VTg + (size_t)r * 4096 + kv0 * 2 + (cbx ^ ((r & 7) << 4)),
                    (char*)&Vtile[b][0][0] + ck * 1024);
        }
    };

    auto qkt = [&](f32x16 (&sT)[2], int b) {
        const char* Kb = (const char*)&Ktile[b][0][0];
#pragma unroll
        for (int s2 = 0; s2 < 2; ++s2)
#pragma unroll
            for (int r = 0; r < 16; ++r) sT[s2][r] = 0.f;
        __builtin_amdgcn_s_setprio(1);
#pragma unroll
        for (int sub = 0; sub < 2; ++sub) {
            int row = sub * 32 + li32;
            int sw  = (row & 7) << 4;
            const char* kbase = Kb + row * 256;
#pragma unroll
            for (int kc = 0; kc < 8; ++kc) {
                short8 kf = *(const short8*)(kbase + ((kc * 32 + hi * 16) ^ sw));
                sT[sub] = __builtin_amdgcn_mfma_f32_32x32x16_bf16(kf, qf[kc], sT[sub], 0, 0, 0);
            }
        }
        __builtin_amdgcn_s_setprio(0);
    };

    auto step = [&](f32x16 (&cur)[2], f32x16 (&next)[2], int t, bool doK, bool doNext) {
        if (doK)    stageK(t + 2, t & 1);
        if (doNext) stageV(t + 1, (t + 1) & 1);
        if (doNext) qkt(next, (t + 1) & 1);        // tile t+1 QK^T, overlaps softmax(t)

        // ---- softmax(t): tree max ----
        float t0[8];
#pragma unroll
        for (int j = 0; j < 8; ++j)
            t0[j] = fmaxf(fmaxf(cur[0][j], cur[0][j + 8]), fmaxf(cur[1][j], cur[1][j + 8]));
        float pm = fmaxf(fmaxf(fmaxf(t0[0], t0[1]), fmaxf(t0[2], t0[3])),
                         fmaxf(fmaxf(t0[4], t0[5]), fmaxf(t0[6], t0[7])));
        pm = fmaxf(pm, __shfl_xor(pm, 32));

        if (__any(pm > m_run + 8.f)) {             // defer-max (log2 domain)
            float mn = fmaxf(m_run, pm);
            float al = fexp2(m_run - mn);
#pragma unroll
            for (int a = 0; a < 2; ++a)
#pragma unroll
                for (int r = 0; r < 16; ++r) o[a][r] *= al;
            l_run *= al;
            m_run = mn;
        }

        // ---- exp2 + pack ----
        float lsp[4] = {0.f, 0.f, 0.f, 0.f};
        int w[2][8];
#pragma unroll
        for (int sub = 0; sub < 2; ++sub)
#pragma unroll
            for (int r2 = 0; r2 < 8; ++r2) {
                float p0 = fexp2(cur[sub][2 * r2]     - m_run);
                float p1 = fexp2(cur[sub][2 * r2 + 1] - m_run);
                lsp[r2 & 3] += p0 + p1;
                w[sub][r2] = cvtpk(p0, p1);
            }
        float ls = (lsp[0] + lsp[1]) + (lsp[2] + lsp[3]);
        ls += __shfl_xor(ls, 32);
        l_run += ls;

        short8 pf[2][2];
#pragma unroll
        for (int sub = 0; sub < 2; ++sub) {
            plswap(w[sub][0], w[sub][2]); plswap(w[sub][1], w[sub][3]);
            plswap(w[sub][4], w[sub][6]); plswap(w[sub][5], w[sub][7]);
            i32x4 f0 = { w[sub][0], w[sub][1], w[sub][2], w[sub][3] };
            i32x4 f1 = { w[sub][4], w[sub][5], w[sub][6], w[sub][7] };
            pf[sub][0] = __builtin_bit_cast(short8, f0);
            pf[sub][1] = __builtin_bit_cast(short8, f1);
        }

        // ---- PV(t) ----
        const char* Vb = (const char*)&Vtile[t & 1][0][0];
        __builtin_amdgcn_s_setprio(1);
#pragma unroll
        for (int sub = 0; sub < 2; ++sub)
#pragma unroll
            for (int ksel = 0; ksel < 2; ++ksel) {
                int cc = sub * 2 + ksel;
#pragma unroll
                for (int a = 0; a < 2; ++a) {
                    int row = a * 32 + li32;
                    int sw  = (row & 7) << 4;
                    short8 vf = *(const short8*)(Vb + row * 128 + ((cc * 32 + hi * 16) ^ sw));
                    o[a] = __builtin_amdgcn_mfma_f32_32x32x16_bf16(vf, pf[sub][ksel], o[a], 0, 0, 0);
                }
            }
        __builtin_amdgcn_s_setprio(0);

        __syncthreads();
    };

    // prologue: K(0), V(0), K(1) staged; compute sT(0)
    stageK(0, 0);
    stageV(0, 0);
    stageK(1, 1);
    __syncthreads();
    f32x16 sA[2], sB[2];
    qkt(sA, 0);
    __syncthreads();     // protect K[0] from stageK(2,0) in step 0

    for (int t = 0; t < 30; t += 2) {
        step(sA, sB, t,     true, true);
        step(sB, sA, t + 1, true, true);
    }
    step(sA, sB, 30, false, true);
    step(sB, sA, 31, false, false);

    // epilogue: O^T -> LDS transpose -> coalesced AO rows
    __hip_bfloat16* AO = ws + OFF_AO;
    int b = bh >> 3, h = bh & 7;
    char* tb = (char*)&Ktile[0][0][0] + wave * 4096;
    float inv = 1.f / l_run;
#pragma unroll
    for (int a = 0; a < 2; ++a)
#pragma unroll
        for (int r2 = 0; r2 < 8; ++r2) {
            int r = 2 * r2;
            int dv = (r & 3) + 8 * (r >> 2) + 4 * hi + 32 * a;
            int word = cvtpk(o[a][r] * inv, o[a][r + 1] * inv);
            *(int*)(tb + li32 * 128 + ((dv * 2) ^ ((li32 & 7) << 4))) = word;
        }
#pragma unroll
    for (int qq = 0; qq < 32; qq += 8) {
        int q = qq + (lane >> 3), seg = lane & 7;
        short8 vrow = *(const short8*)(tb + q * 128 + ((seg * 16) ^ ((q & 7) << 4)));
        *(short8*)(AO + (size_t)(b * N + qr0 + q) * INNER + h * 64 + seg * 8) = vrow;
    }
}

// ---------------- GEMM3: out = AO @ w_out + b_out ----------------
__global__ __launch_bounds__(256) void gemm_out(const __hip_bfloat16* __restrict__ ws_c,
                                                const float* __restrict__ bout,
                                                float* __restrict__ out) {
    const short* AO = (const short*)(ws_c + OFF_AO);
    const short* Bt = (const short*)(ws_c + OFF_WOUTT);
    int m0 = blockIdx.x * 128, n0 = blockIdx.y * 128;

    __shared__ __align__(16) short As[128][64];
    __shared__ __align__(16) short Bs[128][64];

    int tid  = threadIdx.x;
    int wave = tid >> 6, lane = tid & 63;
    int wrow = wave >> 1, wcol = wave & 1;
    int lg = lane >> 4, li = lane & 15;

    f32x4 acc[4][4] = {};

    for (int k0 = 0; k0 < 512; k0 += 64) {
#pragma unroll
        for (int i = 0; i < 4; ++i) {
            int c = wave * 4 + i;
            int r = c * 8 + (lane >> 3);
            gload16((const char*)AO + ((size_t)(m0 + r) * 512 + k0 + (lane & 7) * 8) * 2,
                    (char*)&As[0][0] + c * 1024);
            gload16((const char*)Bt + ((size_t)(n0 + r) * 512 + k0 + (lane & 7) * 8) * 2,
                    (char*)&Bs[0][0] + c * 1024);
        }
        __syncthreads();
#pragma unroll
        for (int ks = 0; ks < 2; ++ks) {
            short8 af[4], bf[4];
#pragma unroll
            for (int m = 0; m < 4; ++m)
                af[m] = *(const short8*)(&As[wrow * 64 + m * 16 + li][ks * 32 + lg * 8]);
#pragma unroll
            for (int n = 0; n < 4; ++n)
                bf[n] = *(const short8*)(&Bs[wcol * 64 + n * 16 + li][ks * 32 + lg * 8]);
#pragma unroll
            for (int m = 0; m < 4; ++m)
#pragma unroll
                for (int n = 0; n < 4; ++n)
                    acc[m][n] = __builtin_amdgcn_mfma_f32_16x16x32_bf16(af[m], bf[n], acc[m][n], 0, 0, 0);
        }
        __syncthreads();
    }
#pragma unroll
    for (int m = 0; m < 4; ++m)
#pragma unroll
        for (int n = 0; n < 4; ++n)
#pragma unroll
            for (int j = 0; j < 4; ++j) {
                int row = m0 + wrow * 64 + m * 16 + lg * 4 + j;
                int col = n0 + wcol * 64 + n * 16 + li;
                out[(size_t)row * 512 + col] = acc[m][n][j] + bout[col];
            }
}

extern "C" void kernel_launch(void* const* d_in, const int* in_sizes, int n_in,
                              void* d_out, int out_size, void* d_ws, size_t ws_size,
                              hipStream_t stream) {
    const float* x    = (const float*)d_in[0];
    const float* bias = (const float*)d_in[1];
    const float* wqkv = (const float*)d_in[2];
    const float* wout = (const float*)d_in[3];
    const float* bout = (const float*)d_in[4];
    float* out = (float*)d_out;
    __hip_bfloat16* ws = (__hip_bfloat16*)d_ws;

    hipLaunchKernelGGL(prep_kernel, dim3(2048), dim3(256), 0, stream, wqkv, wout, x, bias, ws);
    hipLaunchKernelGGL(gemm_qkv, dim3(64, 20), dim3(256), 0, stream, ws);
    hipLaunchKernelGGL(attn_kernel, dim3(512), dim3(256), 0, stream, ws);
    hipLaunchKernelGGL(gemm_out, dim3(64, 4), dim3(256), 0, stream, (const __hip_bfloat16*)ws, bout, out);
}

// Round 8
// 144.779 us; speedup vs baseline: 2.8933x; 1.0009x over previous
//
#include <hip/hip_runtime.h>
#include <hip/hip_bf16.h>

#define DEV __device__ __forceinline__

typedef __attribute__((ext_vector_type(8))) short short8;
typedef __attribute__((ext_vector_type(4))) int i32x4;
typedef __attribute__((ext_vector_type(2))) int i32x2;
typedef __attribute__((ext_vector_type(4))) float f32x4;
typedef __attribute__((ext_vector_type(16))) float f32x16;

constexpr int B = 4, N = 2048, H = 8, DH = 64;
constexpr int INNER = H * DH;          // 512
constexpr int BH = B * H;              // 32
// SCALE * log2(e): QK^T yields log2-domain scores -> v_exp_f32 (2^x) directly
constexpr float QSCALE = 0.125f * 1.44269504088896f;

// ---- workspace layout (bf16 elements) ----
constexpr size_t OFF_WQKVT = 0;                               // [1536][512]
constexpr size_t OFF_WOUTT = OFF_WQKVT + (size_t)1536 * 512;  // [512][512]
constexpr size_t OFF_QT    = OFF_WOUTT + (size_t)512 * 512;   // [32][2048][128]
constexpr size_t OFF_KT    = OFF_QT + (size_t)BH * N * 128;   // [32][2048][128]
constexpr size_t OFF_VT    = OFF_KT + (size_t)BH * N * 128;   // [32][64][2048]
constexpr size_t OFF_AO    = OFF_VT + (size_t)BH * DH * N;    // [8192][512]
constexpr size_t OFF_XBF   = OFF_AO + (size_t)8192 * 512;     // [8192][512] x as bf16
constexpr size_t OFF_BBF   = OFF_AO;                          // bias bf16 (aliases AO; AO written later)

DEV short f2b(float f) {
    __hip_bfloat16 h = __float2bfloat16(f);
    return __builtin_bit_cast(short, h);
}

DEV int cvtpk(float lo, float hi) {
    int r;
    asm("v_cvt_pk_bf16_f32 %0, %1, %2" : "=v"(r) : "v"(lo), "v"(hi));
    return r;
}

DEV float fexp2(float x) {
    float r;
    asm("v_exp_f32 %0, %1" : "=v"(r) : "v"(x));
    return r;
}

DEV void plswap(int& a, int& b) {
    i32x2 r = __builtin_amdgcn_permlane32_swap(a, b, false, false);
    a = r.x; b = r.y;
}

DEV void gload16(const void* g, void* l) {
    __builtin_amdgcn_global_load_lds(
        (const __attribute__((address_space(1))) unsigned int*)g,
        (__attribute__((address_space(3))) unsigned int*)l, 16, 0, 0);
}

// ---------------- prep: weight transpose + x/bias -> bf16 ----------------
__global__ void prep_kernel(const float* __restrict__ wqkv,
                            const float* __restrict__ wout,
                            const float* __restrict__ x,
                            const float* __restrict__ bias,
                            __hip_bfloat16* __restrict__ ws) {
    __hip_bfloat16* wqkvT = ws + OFF_WQKVT;
    __hip_bfloat16* woutT = ws + OFF_WOUTT;
    short8* xbf = (short8*)(ws + OFF_XBF);
    short8* bbf = (short8*)(ws + OFF_BBF);
    int tid = blockIdx.x * blockDim.x + threadIdx.x;
    const int nconv = 8192 * 512 / 8;
    const int t1 = 512 * 1536 / 4;
    const int t2 = 512 * 512 / 4;
    const int total = 2 * nconv + t1 + t2;
    for (int i = tid; i < total; i += gridDim.x * blockDim.x) {
        if (i < 2 * nconv) {
            const float4* src = (const float4*)(i < nconv ? x : bias);
            short8* dst = i < nconv ? xbf : bbf;
            int j = i < nconv ? i : i - nconv;
            float4 v0 = src[2 * j], v1 = src[2 * j + 1];
            short8 sv;
            sv[0] = f2b(v0.x); sv[1] = f2b(v0.y); sv[2] = f2b(v0.z); sv[3] = f2b(v0.w);
            sv[4] = f2b(v1.x); sv[5] = f2b(v1.y); sv[6] = f2b(v1.z); sv[7] = f2b(v1.w);
            dst[j] = sv;
        } else if (i < 2 * nconv + t1) {
            int j = i - 2 * nconv;
            int k  = j / 384;
            int c4 = (j % 384) * 4;
            float4 v = ((const float4*)wqkv)[j];
            wqkvT[(size_t)(c4 + 0) * 512 + k] = __float2bfloat16(v.x);
            wqkvT[(size_t)(c4 + 1) * 512 + k] = __float2bfloat16(v.y);
            wqkvT[(size_t)(c4 + 2) * 512 + k] = __float2bfloat16(v.z);
            wqkvT[(size_t)(c4 + 3) * 512 + k] = __float2bfloat16(v.w);
        } else {
            int j = i - 2 * nconv - t1;
            int k  = j / 128;
            int c4 = (j % 128) * 4;
            float4 v = ((const float4*)wout)[j];
            woutT[(size_t)(c4 + 0) * 512 + k] = __float2bfloat16(v.x);
            woutT[(size_t)(c4 + 1) * 512 + k] = __float2bfloat16(v.y);
            woutT[(size_t)(c4 + 2) * 512 + k] = __float2bfloat16(v.z);
            woutT[(size_t)(c4 + 3) * 512 + k] = __float2bfloat16(v.w);
        }
    }
}

// ---------------- GEMM1: qkv = {x,bias}@w_qkv -> QT/KT/VT ----------------
// grid (64, 20): yt 0..11 = x (all 1536 cols), yt 12..19 = bias (cols 0..1023)
__global__ __launch_bounds__(256) void gemm_qkv(__hip_bfloat16* __restrict__ ws) {
    int mt = blockIdx.x, yt = blockIdx.y;
    bool src_is_bias = (yt >= 12);
    int nt = src_is_bias ? yt - 12 : yt;
    const short* A  = (const short*)(ws + (src_is_bias ? OFF_BBF : OFF_XBF));
    const short* Bt = (const short*)(ws + OFF_WQKVT);
    int m0 = mt * 128, n0 = nt * 128;

    __shared__ __align__(16) short As[128][64];
    __shared__ __align__(16) short Bs[128][64];

    int tid  = threadIdx.x;
    int wave = tid >> 6, lane = tid & 63;
    int wrow = wave >> 1, wcol = wave & 1;
    int lg = lane >> 4, li = lane & 15;

    f32x4 acc[4][4] = {};

    for (int k0 = 0; k0 < 512; k0 += 64) {
#pragma unroll
        for (int i = 0; i < 4; ++i) {
            int c = wave * 4 + i;
            int r = c * 8 + (lane >> 3);
            gload16((const char*)A + ((size_t)(m0 + r) * 512 + k0 + (lane & 7) * 8) * 2,
                    (char*)&As[0][0] + c * 1024);
            gload16((const char*)Bt + ((size_t)(n0 + r) * 512 + k0 + (lane & 7) * 8) * 2,
                    (char*)&Bs[0][0] + c * 1024);
        }
        __syncthreads();
#pragma unroll
        for (int ks = 0; ks < 2; ++ks) {
            short8 af[4], bf[4];
#pragma unroll
            for (int m = 0; m < 4; ++m)
                af[m] = *(const short8*)(&As[wrow * 64 + m * 16 + li][ks * 32 + lg * 8]);
#pragma unroll
            for (int n = 0; n < 4; ++n)
                bf[n] = *(const short8*)(&Bs[wcol * 64 + n * 16 + li][ks * 32 + lg * 8]);
#pragma unroll
            for (int m = 0; m < 4; ++m)
#pragma unroll
                for (int n = 0; n < 4; ++n)
                    acc[m][n] = __builtin_amdgcn_mfma_f32_16x16x32_bf16(af[m], bf[n], acc[m][n], 0, 0, 0);
        }
        __syncthreads();
    }

    __hip_bfloat16* QT = ws + OFF_QT;
    __hip_bfloat16* KT = ws + OFF_KT;
    __hip_bfloat16* VT = ws + OFF_VT;
    int qkoff = src_is_bias ? 64 : 0;
#pragma unroll
    for (int m = 0; m < 4; ++m)
#pragma unroll
        for (int n = 0; n < 4; ++n)
#pragma unroll
            for (int j = 0; j < 4; ++j) {
                int row = m0 + wrow * 64 + m * 16 + lg * 4 + j;
                int col = n0 + wcol * 64 + n * 16 + li;
                float v = acc[m][n][j];
                int b = row >> 11, nn = row & 2047;
                if (col < 512) {
                    int h = col >> 6, d = col & 63;
                    QT[((size_t)(b * H + h) * N + nn) * 128 + d + qkoff] = __float2bfloat16(v * QSCALE);
                } else if (col < 1024) {
                    int c = col - 512; int h = c >> 6, d = c & 63;
                    KT[((size_t)(b * H + h) * N + nn) * 128 + d + qkoff] = __float2bfloat16(v);
                } else {
                    int c = col - 1024; int h = c >> 6, d = c & 63;
                    VT[((size_t)(b * H + h) * DH + d) * N + nn] = __float2bfloat16(v);
                }
            }
}

// ---------------- flash attention: 32x32 MFMA, log2 defer-max softmax (proven R4 math) ----------------
// grid 512 = 8 XCD-groups x 4 bh x 16 qblocks; 4 waves x 32 q each.
__global__ __launch_bounds__(256, 3) void attn_kernel(__hip_bfloat16* __restrict__ ws) {
    int bid = blockIdx.x;
    int c   = bid & 7;
    int idx = bid >> 3;
    int bh  = (idx & 3) * 8 + c;      // 4 bh per XCD -> K/V L2-resident
    int qb  = idx >> 2;

    int wave = threadIdx.x >> 6, lane = threadIdx.x & 63;
    int li32 = lane & 31, hi = lane >> 5;
    int qr0 = qb * 128 + wave * 32;

    const short* QT  = (const short*)(ws + OFF_QT) + (size_t)bh * N * 128;
    const char*  KTg = (const char*)((const short*)(ws + OFF_KT) + (size_t)bh * N * 128);
    const char*  VTg = (const char*)((const short*)(ws + OFF_VT) + (size_t)bh * DH * N);

    __shared__ __align__(16) short Ktile[2][64][128];   // 32 KB dbuf
    __shared__ __align__(16) short Vtile[2][64][64];    // 16 KB dbuf

    short8 qf[8];
#pragma unroll
    for (int kc = 0; kc < 8; ++kc)
        qf[kc] = *(const short8*)(QT + (size_t)(qr0 + li32) * 128 + kc * 16 + hi * 8);

    float m_run = -3e38f, l_run = 0.f;   // l_run: per-lane half-row sum; cross-half add in epilogue
    f32x16 o[2] = {};

    auto stage = [&](int t, int b) {
        int kv0 = t * 64;
#pragma unroll
        for (int cc = 0; cc < 4; ++cc) {          // K: 16 KB, 4 chunks/wave
            int ck = wave * 4 + cc;
            int r  = ck * 4 + (lane >> 4);
            int cbx = (lane & 15) * 16;
            gload16(KTg + (size_t)(kv0 + r) * 256 + (cbx ^ ((r & 7) << 4)),
                    (char*)&Ktile[b][0][0] + ck * 1024);
        }
#pragma unroll
        for (int cc = 0; cc < 2; ++cc) {          // V: 8 KB, 2 chunks/wave
            int ck = wave * 2 + cc;
            int r  = ck * 8 + (lane >> 3);
            int cbx = (lane & 7) * 16;
            gload16(VTg + (size_t)r * 4096 + kv0 * 2 + (cbx ^ ((r & 7) << 4)),
                    (char*)&Vtile[b][0][0] + ck * 1024);
        }
    };

    stage(0, 0);
    __syncthreads();
    int buf = 0;

    for (int t = 0; t < N / 64; ++t) {
        if (t + 1 < N / 64) stage(t + 1, buf ^ 1);
        const char* Kb = (const char*)&Ktile[buf][0][0];
        const char* Vb = (const char*)&Vtile[buf][0][0];

        // S^T[kv][q]: sT[sub], kv = sub*32 + (r&3)+8*(r>>2)+4*hi, q = li32 (log2 domain)
        f32x16 sT[2] = {};
        __builtin_amdgcn_s_setprio(1);
#pragma unroll
        for (int sub = 0; sub < 2; ++sub) {
            int row = sub * 32 + li32;
            int sw  = (row & 7) << 4;
            const char* kbase = Kb + row * 256;
#pragma unroll
            for (int kc = 0; kc < 8; ++kc) {
                short8 kf = *(const short8*)(kbase + ((kc * 32 + hi * 16) ^ sw));
                sT[sub] = __builtin_amdgcn_mfma_f32_32x32x16_bf16(kf, qf[kc], sT[sub], 0, 0, 0);
            }
        }
        __builtin_amdgcn_s_setprio(0);

        // tree max over this tile (per q = li32)
        float t0[8];
#pragma unroll
        for (int j = 0; j < 8; ++j)
            t0[j] = fmaxf(fmaxf(sT[0][j], sT[0][j + 8]), fmaxf(sT[1][j], sT[1][j + 8]));
        float pm = fmaxf(fmaxf(fmaxf(t0[0], t0[1]), fmaxf(t0[2], t0[3])),
                         fmaxf(fmaxf(t0[4], t0[5]), fmaxf(t0[6], t0[7])));
        pm = fmaxf(pm, __shfl_xor(pm, 32));

        // defer-max (T13, THR=8 in log2 domain)
        if (__any(pm > m_run + 8.f)) {
            float mn = fmaxf(m_run, pm);
            float al = fexp2(m_run - mn);
#pragma unroll
            for (int a = 0; a < 2; ++a)
#pragma unroll
                for (int r = 0; r < 16; ++r) o[a][r] *= al;
            l_run *= al;
            m_run = mn;
        }

        // exp2 + pack to bf16 words
        float lsp[4] = {0.f, 0.f, 0.f, 0.f};
        int w[2][8];
#pragma unroll
        for (int sub = 0; sub < 2; ++sub)
#pragma unroll
            for (int r2 = 0; r2 < 8; ++r2) {
                float p0 = fexp2(sT[sub][2 * r2]     - m_run);
                float p1 = fexp2(sT[sub][2 * r2 + 1] - m_run);
                lsp[r2 & 3] += p0 + p1;
                w[sub][r2] = cvtpk(p0, p1);
            }
        l_run += (lsp[0] + lsp[1]) + (lsp[2] + lsp[3]);

        // P^T B-fragments via permlane32_swap (T12)
        short8 pf[2][2];
#pragma unroll
        for (int sub = 0; sub < 2; ++sub) {
            plswap(w[sub][0], w[sub][2]); plswap(w[sub][1], w[sub][3]);
            plswap(w[sub][4], w[sub][6]); plswap(w[sub][5], w[sub][7]);
            i32x4 f0 = { w[sub][0], w[sub][1], w[sub][2], w[sub][3] };
            i32x4 f1 = { w[sub][4], w[sub][5], w[sub][6], w[sub][7] };
            pf[sub][0] = __builtin_bit_cast(short8, f0);
            pf[sub][1] = __builtin_bit_cast(short8, f1);
        }

        // PV: O^T[dv][q] += V^T[dv][kv] * P^T[kv][q]
        __builtin_amdgcn_s_setprio(1);
#pragma unroll
        for (int sub = 0; sub < 2; ++sub)
#pragma unroll
            for (int ksel = 0; ksel < 2; ++ksel) {
                int cc = sub * 2 + ksel;
#pragma unroll
                for (int a = 0; a < 2; ++a) {
                    int row = a * 32 + li32;
                    int sw  = (row & 7) << 4;
                    short8 vf = *(const short8*)(Vb + row * 128 + ((cc * 32 + hi * 16) ^ sw));
                    o[a] = __builtin_amdgcn_mfma_f32_32x32x16_bf16(vf, pf[sub][ksel], o[a], 0, 0, 0);
                }
            }
        __builtin_amdgcn_s_setprio(0);

        __syncthreads();
        buf ^= 1;
    }

    // epilogue: O^T -> LDS transpose -> coalesced AO rows
    l_run += __shfl_xor(l_run, 32);    // combine the two half-row sums (both halves share m_run)
    __hip_bfloat16* AO = ws + OFF_AO;
    int b = bh >> 3, h = bh & 7;
    char* tb = (char*)&Ktile[0][0][0] + wave * 4096;
    float inv = 1.f / l_run;
#pragma unroll
    for (int a = 0; a < 2; ++a)
#pragma unroll
        for (int r2 = 0; r2 < 8; ++r2) {
            int r = 2 * r2;
            int dv = (r & 3) + 8 * (r >> 2) + 4 * hi + 32 * a;
            int word = cvtpk(o[a][r] * inv, o[a][r + 1] * inv);
            *(int*)(tb + li32 * 128 + ((dv * 2) ^ ((li32 & 7) << 4))) = word;
        }
#pragma unroll
    for (int qq = 0; qq < 32; qq += 8) {
        int q = qq + (lane >> 3), seg = lane & 7;
        short8 vrow = *(const short8*)(tb + q * 128 + ((seg * 16) ^ ((q & 7) << 4)));
        *(short8*)(AO + (size_t)(b * N + qr0 + q) * INNER + h * 64 + seg * 8) = vrow;
    }
}

// ---------------- GEMM3: out = AO @ w_out + b_out ----------------
__global__ __launch_bounds__(256) void gemm_out(const __hip_bfloat16* __restrict__ ws_c,
                                                const float* __restrict__ bout,
                                                float* __restrict__ out) {
    const short* AO = (const short*)(ws_c + OFF_AO);
    const short* Bt = (const short*)(ws_c + OFF_WOUTT);
    int m0 = blockIdx.x * 128, n0 = blockIdx.y * 128;

    __shared__ __align__(16) short As[128][64];
    __shared__ __align__(16) short Bs[128][64];

    int tid  = threadIdx.x;
    int wave = tid >> 6, lane = tid & 63;
    int wrow = wave >> 1, wcol = wave & 1;
    int lg = lane >> 4, li = lane & 15;

    f32x4 acc[4][4] = {};

    for (int k0 = 0; k0 < 512; k0 += 64) {
#pragma unroll
        for (int i = 0; i < 4; ++i) {
            int c = wave * 4 + i;
            int r = c * 8 + (lane >> 3);
            gload16((const char*)AO + ((size_t)(m0 + r) * 512 + k0 + (lane & 7) * 8) * 2,
                    (char*)&As[0][0] + c * 1024);
            gload16((const char*)Bt + ((size_t)(n0 + r) * 512 + k0 + (lane & 7) * 8) * 2,
                    (char*)&Bs[0][0] + c * 1024);
        }
        __syncthreads();
#pragma unroll
        for (int ks = 0; ks < 2; ++ks) {
            short8 af[4], bf[4];
#pragma unroll
            for (int m = 0; m < 4; ++m)
                af[m] = *(const short8*)(&As[wrow * 64 + m * 16 + li][ks * 32 + lg * 8]);
#pragma unroll
            for (int n = 0; n < 4; ++n)
                bf[n] = *(const short8*)(&Bs[wcol * 64 + n * 16 + li][ks * 32 + lg * 8]);
#pragma unroll
            for (int m = 0; m < 4; ++m)
#pragma unroll
                for (int n = 0; n < 4; ++n)
                    acc[m][n] = __builtin_amdgcn_mfma_f32_16x16x32_bf16(af[m], bf[n], acc[m][n], 0, 0, 0);
        }
        __syncthreads();
    }
#pragma unroll
    for (int m = 0; m < 4; ++m)
#pragma unroll
        for (int n = 0; n < 4; ++n)
#pragma unroll
            for (int j = 0; j < 4; ++j) {
                int row = m0 + wrow * 64 + m * 16 + lg * 4 + j;
                int col = n0 + wcol * 64 + n * 16 + li;
                out[(size_t)row * 512 + col] = acc[m][n][j] + bout[col];
            }
}

extern "C" void kernel_launch(void* const* d_in, const int* in_sizes, int n_in,
                              void* d_out, int out_size, void* d_ws, size_t ws_size,
                              hipStream_t stream) {
    const float* x    = (const float*)d_in[0];
    const float* bias = (const float*)d_in[1];
    const float* wqkv = (const float*)d_in[2];
    const float* wout = (const float*)d_in[3];
    const float* bout = (const float*)d_in[4];
    float* out = (float*)d_out;
    __hip_bfloat16* ws = (__hip_bfloat16*)d_ws;

    hipLaunchKernelGGL(prep_kernel, dim3(2048), dim3(256), 0, stream, wqkv, wout, x, bias, ws);
    hipLaunchKernelGGL(gemm_qkv, dim3(64, 20), dim3(256), 0, stream, ws);
    hipLaunchKernelGGL(attn_kernel, dim3(512), dim3(256), 0, stream, ws);
    hipLaunchKernelGGL(gemm_out, dim3(64, 4), dim3(256), 0, stream, (const __hip_bfloat16*)ws, bout, out);
}

// Round 9
// 139.236 us; speedup vs baseline: 3.0085x; 1.0398x over previous
//
#include <hip/hip_runtime.h>
#include <hip/hip_bf16.h>

#define DEV __device__ __forceinline__

typedef __attribute__((ext_vector_type(8))) short short8;
typedef __attribute__((ext_vector_type(4))) int i32x4;
typedef __attribute__((ext_vector_type(2))) int i32x2;
typedef __attribute__((ext_vector_type(4))) float f32x4;
typedef __attribute__((ext_vector_type(16))) float f32x16;

constexpr int B = 4, N = 2048, H = 8, DH = 64;
constexpr int INNER = H * DH;          // 512
constexpr int BH = B * H;              // 32
// SCALE * log2(e): QK^T yields log2-domain scores -> v_exp_f32 (2^x) directly
constexpr float QSCALE = 0.125f * 1.44269504088896f;

// ---- workspace layout (bf16 elements) ----
constexpr size_t OFF_WQKVT = 0;                               // [1536][512]
constexpr size_t OFF_WOUTT = OFF_WQKVT + (size_t)1536 * 512;  // [512][512]
constexpr size_t OFF_QT    = OFF_WOUTT + (size_t)512 * 512;   // [32][2048][128]
constexpr size_t OFF_KT    = OFF_QT + (size_t)BH * N * 128;   // [32][2048][128]
constexpr size_t OFF_VT    = OFF_KT + (size_t)BH * N * 128;   // [32][64][2048]
constexpr size_t OFF_AO    = OFF_VT + (size_t)BH * DH * N;    // [8192][512]
constexpr size_t OFF_XBF   = OFF_AO + (size_t)8192 * 512;     // [8192][512] x as bf16
constexpr size_t OFF_BBF   = OFF_AO;                          // bias bf16 (aliases AO; AO written later)

DEV short f2b(float f) {
    __hip_bfloat16 h = __float2bfloat16(f);
    return __builtin_bit_cast(short, h);
}

DEV int cvtpk(float lo, float hi) {
    int r;
    asm("v_cvt_pk_bf16_f32 %0, %1, %2" : "=v"(r) : "v"(lo), "v"(hi));
    return r;
}

DEV float fexp2(float x) {
    float r;
    asm("v_exp_f32 %0, %1" : "=v"(r) : "v"(x));
    return r;
}

DEV void plswap(int& a, int& b) {
    i32x2 r = __builtin_amdgcn_permlane32_swap(a, b, false, false);
    a = r.x; b = r.y;
}

DEV void gload16(const void* g, void* l) {
    __builtin_amdgcn_global_load_lds(
        (const __attribute__((address_space(1))) unsigned int*)g,
        (__attribute__((address_space(3))) unsigned int*)l, 16, 0, 0);
}

// ---------------- prep: weight transpose + x/bias -> bf16 ----------------
__global__ void prep_kernel(const float* __restrict__ wqkv,
                            const float* __restrict__ wout,
                            const float* __restrict__ x,
                            const float* __restrict__ bias,
                            __hip_bfloat16* __restrict__ ws) {
    __hip_bfloat16* wqkvT = ws + OFF_WQKVT;
    __hip_bfloat16* woutT = ws + OFF_WOUTT;
    short8* xbf = (short8*)(ws + OFF_XBF);
    short8* bbf = (short8*)(ws + OFF_BBF);
    int tid = blockIdx.x * blockDim.x + threadIdx.x;
    const int nconv = 8192 * 512 / 8;
    const int t1 = 512 * 1536 / 4;
    const int t2 = 512 * 512 / 4;
    const int total = 2 * nconv + t1 + t2;
    for (int i = tid; i < total; i += gridDim.x * blockDim.x) {
        if (i < 2 * nconv) {
            const float4* src = (const float4*)(i < nconv ? x : bias);
            short8* dst = i < nconv ? xbf : bbf;
            int j = i < nconv ? i : i - nconv;
            float4 v0 = src[2 * j], v1 = src[2 * j + 1];
            short8 sv;
            sv[0] = f2b(v0.x); sv[1] = f2b(v0.y); sv[2] = f2b(v0.z); sv[3] = f2b(v0.w);
            sv[4] = f2b(v1.x); sv[5] = f2b(v1.y); sv[6] = f2b(v1.z); sv[7] = f2b(v1.w);
            dst[j] = sv;
        } else if (i < 2 * nconv + t1) {
            int j = i - 2 * nconv;
            int k  = j / 384;
            int c4 = (j % 384) * 4;
            float4 v = ((const float4*)wqkv)[j];
            wqkvT[(size_t)(c4 + 0) * 512 + k] = __float2bfloat16(v.x);
            wqkvT[(size_t)(c4 + 1) * 512 + k] = __float2bfloat16(v.y);
            wqkvT[(size_t)(c4 + 2) * 512 + k] = __float2bfloat16(v.z);
            wqkvT[(size_t)(c4 + 3) * 512 + k] = __float2bfloat16(v.w);
        } else {
            int j = i - 2 * nconv - t1;
            int k  = j / 128;
            int c4 = (j % 128) * 4;
            float4 v = ((const float4*)wout)[j];
            woutT[(size_t)(c4 + 0) * 512 + k] = __float2bfloat16(v.x);
            woutT[(size_t)(c4 + 1) * 512 + k] = __float2bfloat16(v.y);
            woutT[(size_t)(c4 + 2) * 512 + k] = __float2bfloat16(v.z);
            woutT[(size_t)(c4 + 3) * 512 + k] = __float2bfloat16(v.w);
        }
    }
}

// ---------------- GEMM1: qkv = {x,bias}@w_qkv -> QT/KT/VT ----------------
// grid (64, 20): yt 0..11 = x (all 1536 cols), yt 12..19 = bias (cols 0..1023)
// Q/K tiles computed with SWAPPED mfma operands (lane holds token-row, 4 consec cols -> 8B stores);
// V tiles use original orientation (lane holds d-col, 4 consec tokens -> 8B stores to VT[d][n]).
__global__ __launch_bounds__(256) void gemm_qkv(__hip_bfloat16* __restrict__ ws) {
    int mt = blockIdx.x, yt = blockIdx.y;
    bool src_is_bias = (yt >= 12);
    int nt = src_is_bias ? yt - 12 : yt;
    const short* A  = (const short*)(ws + (src_is_bias ? OFF_BBF : OFF_XBF));
    const short* Bt = (const short*)(ws + OFF_WQKVT);
    int m0 = mt * 128, n0 = nt * 128;
    bool isV = (!src_is_bias && nt >= 8);

    __shared__ __align__(16) short As[128][64];
    __shared__ __align__(16) short Bs[128][64];

    int tid  = threadIdx.x;
    int wave = tid >> 6, lane = tid & 63;
    int wrow = wave >> 1, wcol = wave & 1;
    int lg = lane >> 4, li = lane & 15;

    f32x4 acc[4][4] = {};

    auto kloop = [&](bool swp) {
        for (int k0 = 0; k0 < 512; k0 += 64) {
#pragma unroll
            for (int i = 0; i < 4; ++i) {
                int c = wave * 4 + i;
                int r = c * 8 + (lane >> 3);
                gload16((const char*)A + ((size_t)(m0 + r) * 512 + k0 + (lane & 7) * 8) * 2,
                        (char*)&As[0][0] + c * 1024);
                gload16((const char*)Bt + ((size_t)(n0 + r) * 512 + k0 + (lane & 7) * 8) * 2,
                        (char*)&Bs[0][0] + c * 1024);
            }
            __syncthreads();
#pragma unroll
            for (int ks = 0; ks < 2; ++ks) {
                short8 af[4], bf[4];
#pragma unroll
                for (int m = 0; m < 4; ++m)
                    af[m] = *(const short8*)(&As[wrow * 64 + m * 16 + li][ks * 32 + lg * 8]);
#pragma unroll
                for (int n = 0; n < 4; ++n)
                    bf[n] = *(const short8*)(&Bs[wcol * 64 + n * 16 + li][ks * 32 + lg * 8]);
#pragma unroll
                for (int m = 0; m < 4; ++m)
#pragma unroll
                    for (int n = 0; n < 4; ++n)
                        acc[m][n] = swp
                            ? __builtin_amdgcn_mfma_f32_16x16x32_bf16(bf[n], af[m], acc[m][n], 0, 0, 0)
                            : __builtin_amdgcn_mfma_f32_16x16x32_bf16(af[m], bf[n], acc[m][n], 0, 0, 0);
            }
            __syncthreads();
        }
    };
    if (isV) kloop(false); else kloop(true);

    __hip_bfloat16* QT = ws + OFF_QT;
    __hip_bfloat16* KT = ws + OFF_KT;
    __hip_bfloat16* VT = ws + OFF_VT;

    if (isV) {
        // original orientation: lane holds col cc (d) fixed, rows (tokens) lg*4+j
        int cc_base = n0 - 1024 + wcol * 64;
#pragma unroll
        for (int m = 0; m < 4; ++m) {
            int row0 = m0 + wrow * 64 + m * 16 + lg * 4;
            int b = row0 >> 11, nn = row0 & 2047;
#pragma unroll
            for (int n = 0; n < 4; ++n) {
                int cc = cc_base + n * 16 + li;
                int h = cc >> 6, d = cc & 63;
                int w0 = cvtpk(acc[m][n][0], acc[m][n][1]);
                int w1 = cvtpk(acc[m][n][2], acc[m][n][3]);
                short* p = (short*)VT + (size_t)((b * H + h) * DH + d) * N + nn;
                i32x2 wv = { w0, w1 };
                *(i32x2*)p = wv;
            }
        }
    } else {
        // swapped orientation: lane holds token row fixed (li), 4 consecutive cols lg*4+j
        int qkoff = src_is_bias ? 64 : 0;
        bool isQ = (n0 < 512);
#pragma unroll
        for (int m = 0; m < 4; ++m) {
            int row = m0 + wrow * 64 + m * 16 + li;
            int b = row >> 11, nn = row & 2047;
#pragma unroll
            for (int n = 0; n < 4; ++n) {
                int cc0 = n0 + wcol * 64 + n * 16 + lg * 4;
                int w0, w1;
                short* p;
                if (isQ) {
                    int h = cc0 >> 6, d0 = (cc0 & 63) + qkoff;
                    w0 = cvtpk(acc[m][n][0] * QSCALE, acc[m][n][1] * QSCALE);
                    w1 = cvtpk(acc[m][n][2] * QSCALE, acc[m][n][3] * QSCALE);
                    p = (short*)QT + ((size_t)(b * H + h) * N + nn) * 128 + d0;
                } else {
                    int c = cc0 - 512;
                    int h = c >> 6, d0 = (c & 63) + qkoff;
                    w0 = cvtpk(acc[m][n][0], acc[m][n][1]);
                    w1 = cvtpk(acc[m][n][2], acc[m][n][3]);
                    p = (short*)KT + ((size_t)(b * H + h) * N + nn) * 128 + d0;
                }
                i32x2 wv = { w0, w1 };
                *(i32x2*)p = wv;
            }
        }
    }
}

// ---------------- flash attention: 32x32 MFMA, log2 defer-max softmax, unroll-2 ----------------
// grid 512 = 8 XCD-groups x 4 bh x 16 qblocks; 4 waves x 32 q each.
__global__ __launch_bounds__(256, 3) void attn_kernel(__hip_bfloat16* __restrict__ ws) {
    int bid = blockIdx.x;
    int c   = bid & 7;
    int idx = bid >> 3;
    int bh  = (idx & 3) * 8 + c;      // 4 bh per XCD -> K/V L2-resident
    int qb  = idx >> 2;

    int wave = threadIdx.x >> 6, lane = threadIdx.x & 63;
    int li32 = lane & 31, hi = lane >> 5;
    int qr0 = qb * 128 + wave * 32;

    const short* QT  = (const short*)(ws + OFF_QT) + (size_t)bh * N * 128;
    const char*  KTg = (const char*)((const short*)(ws + OFF_KT) + (size_t)bh * N * 128);
    const char*  VTg = (const char*)((const short*)(ws + OFF_VT) + (size_t)bh * DH * N);

    __shared__ __align__(16) short Ktile[2][64][128];   // 32 KB dbuf
    __shared__ __align__(16) short Vtile[2][64][64];    // 16 KB dbuf

    short8 qf[8];
#pragma unroll
    for (int kc = 0; kc < 8; ++kc)
        qf[kc] = *(const short8*)(QT + (size_t)(qr0 + li32) * 128 + kc * 16 + hi * 8);

    float m_run = -3e38f, l_run = 0.f;   // l_run: per-lane half-row sum; cross-half add in epilogue
    f32x16 o[2] = {};

    auto stage = [&](int t, int b) {
        int kv0 = t * 64;
#pragma unroll
        for (int cc = 0; cc < 4; ++cc) {          // K: 16 KB, 4 chunks/wave
            int ck = wave * 4 + cc;
            int r  = ck * 4 + (lane >> 4);
            int cbx = (lane & 15) * 16;
            gload16(KTg + (size_t)(kv0 + r) * 256 + (cbx ^ ((r & 7) << 4)),
                    (char*)&Ktile[b][0][0] + ck * 1024);
        }
#pragma unroll
        for (int cc = 0; cc < 2; ++cc) {          // V: 8 KB, 2 chunks/wave
            int ck = wave * 2 + cc;
            int r  = ck * 8 + (lane >> 3);
            int cbx = (lane & 7) * 16;
            gload16(VTg + (size_t)r * 4096 + kv0 * 2 + (cbx ^ ((r & 7) << 4)),
                    (char*)&Vtile[b][0][0] + ck * 1024);
        }
    };

    // compile-time per-buffer base pointers -> all LDS read addresses loop-invariant
    const char* Kb0 = (const char*)&Ktile[0][0][0];
    const char* Kb1 = (const char*)&Ktile[1][0][0];
    const char* Vb0 = (const char*)&Vtile[0][0][0];
    const char* Vb1 = (const char*)&Vtile[1][0][0];

    auto tile = [&](const char* Kb, const char* Vb) {
        // S^T[kv][q]: sT[sub], kv = sub*32 + (r&3)+8*(r>>2)+4*hi, q = li32 (log2 domain)
        f32x16 sT[2] = {};
        __builtin_amdgcn_s_setprio(1);
#pragma unroll
        for (int sub = 0; sub < 2; ++sub) {
            int row = sub * 32 + li32;
            int sw  = (row & 7) << 4;
            const char* kbase = Kb + row * 256;
#pragma unroll
            for (int kc = 0; kc < 8; ++kc) {
                short8 kf = *(const short8*)(kbase + ((kc * 32 + hi * 16) ^ sw));
                sT[sub] = __builtin_amdgcn_mfma_f32_32x32x16_bf16(kf, qf[kc], sT[sub], 0, 0, 0);
            }
        }
        __builtin_amdgcn_s_setprio(0);

        // tree max over this tile (per q = li32)
        float t0[8];
#pragma unroll
        for (int j = 0; j < 8; ++j)
            t0[j] = fmaxf(fmaxf(sT[0][j], sT[0][j + 8]), fmaxf(sT[1][j], sT[1][j + 8]));
        float pm = fmaxf(fmaxf(fmaxf(t0[0], t0[1]), fmaxf(t0[2], t0[3])),
                         fmaxf(fmaxf(t0[4], t0[5]), fmaxf(t0[6], t0[7])));
        pm = fmaxf(pm, __shfl_xor(pm, 32));

        // defer-max (T13, THR=8 in log2 domain)
        if (__any(pm > m_run + 8.f)) {
            float mn = fmaxf(m_run, pm);
            float al = fexp2(m_run - mn);
#pragma unroll
            for (int a = 0; a < 2; ++a)
#pragma unroll
                for (int r = 0; r < 16; ++r) o[a][r] *= al;
            l_run *= al;
            m_run = mn;
        }

        // exp2 + pack to bf16 words
        float lsp[4] = {0.f, 0.f, 0.f, 0.f};
        int w[2][8];
#pragma unroll
        for (int sub = 0; sub < 2; ++sub)
#pragma unroll
            for (int r2 = 0; r2 < 8; ++r2) {
                float p0 = fexp2(sT[sub][2 * r2]     - m_run);
                float p1 = fexp2(sT[sub][2 * r2 + 1] - m_run);
                lsp[r2 & 3] += p0 + p1;
                w[sub][r2] = cvtpk(p0, p1);
            }
        l_run += (lsp[0] + lsp[1]) + (lsp[2] + lsp[3]);

        // P^T B-fragments via permlane32_swap (T12)
        short8 pf[2][2];
#pragma unroll
        for (int sub = 0; sub < 2; ++sub) {
            plswap(w[sub][0], w[sub][2]); plswap(w[sub][1], w[sub][3]);
            plswap(w[sub][4], w[sub][6]); plswap(w[sub][5], w[sub][7]);
            i32x4 f0 = { w[sub][0], w[sub][1], w[sub][2], w[sub][3] };
            i32x4 f1 = { w[sub][4], w[sub][5], w[sub][6], w[sub][7] };
            pf[sub][0] = __builtin_bit_cast(short8, f0);
            pf[sub][1] = __builtin_bit_cast(short8, f1);
        }

        // PV: O^T[dv][q] += V^T[dv][kv] * P^T[kv][q]
        __builtin_amdgcn_s_setprio(1);
#pragma unroll
        for (int sub = 0; sub < 2; ++sub)
#pragma unroll
            for (int ksel = 0; ksel < 2; ++ksel) {
                int cc = sub * 2 + ksel;
#pragma unroll
                for (int a = 0; a < 2; ++a) {
                    int row = a * 32 + li32;
                    int sw  = (row & 7) << 4;
                    short8 vf = *(const short8*)(Vb + row * 128 + ((cc * 32 + hi * 16) ^ sw));
                    o[a] = __builtin_amdgcn_mfma_f32_32x32x16_bf16(vf, pf[sub][ksel], o[a], 0, 0, 0);
                }
            }
        __builtin_amdgcn_s_setprio(0);

        __syncthreads();
    };

    stage(0, 0);
    __syncthreads();

    for (int t = 0; t < 32; t += 2) {
        stage(t + 1, 1);                  // t <= 30 -> t+1 <= 31, always valid
        tile(Kb0, Vb0);
        if (t + 2 < 32) stage(t + 2, 0);
        tile(Kb1, Vb1);
    }

    // epilogue: O^T -> LDS transpose -> coalesced AO rows
    l_run += __shfl_xor(l_run, 32);    // combine the two half-row sums (both halves share m_run)
    __hip_bfloat16* AO = ws + OFF_AO;
    int b = bh >> 3, h = bh & 7;
    char* tb = (char*)&Ktile[0][0][0] + wave * 4096;
    float inv = 1.f / l_run;
#pragma unroll
    for (int a = 0; a < 2; ++a)
#pragma unroll
        for (int r2 = 0; r2 < 8; ++r2) {
            int r = 2 * r2;
            int dv = (r & 3) + 8 * (r >> 2) + 4 * hi + 32 * a;
            int word = cvtpk(o[a][r] * inv, o[a][r + 1] * inv);
            *(int*)(tb + li32 * 128 + ((dv * 2) ^ ((li32 & 7) << 4))) = word;
        }
#pragma unroll
    for (int qq = 0; qq < 32; qq += 8) {
        int q = qq + (lane >> 3), seg = lane & 7;
        short8 vrow = *(const short8*)(tb + q * 128 + ((seg * 16) ^ ((q & 7) << 4)));
        *(short8*)(AO + (size_t)(b * N + qr0 + q) * INNER + h * 64 + seg * 8) = vrow;
    }
}

// ---------------- GEMM3: out = AO @ w_out + b_out (swapped operands -> float4 stores) ----------------
__global__ __launch_bounds__(256) void gemm_out(const __hip_bfloat16* __restrict__ ws_c,
                                                const float* __restrict__ bout,
                                                float* __restrict__ out) {
    const short* AO = (const short*)(ws_c + OFF_AO);
    const short* Bt = (const short*)(ws_c + OFF_WOUTT);
    int m0 = blockIdx.x * 128, n0 = blockIdx.y * 128;

    __shared__ __align__(16) short As[128][64];
    __shared__ __align__(16) short Bs[128][64];

    int tid  = threadIdx.x;
    int wave = tid >> 6, lane = tid & 63;
    int wrow = wave >> 1, wcol = wave & 1;
    int lg = lane >> 4, li = lane & 15;

    f32x4 acc[4][4] = {};

    for (int k0 = 0; k0 < 512; k0 += 64) {
#pragma unroll
        for (int i = 0; i < 4; ++i) {
            int c = wave * 4 + i;
            int r = c * 8 + (lane >> 3);
            gload16((const char*)AO + ((size_t)(m0 + r) * 512 + k0 + (lane & 7) * 8) * 2,
                    (char*)&As[0][0] + c * 1024);
            gload16((const char*)Bt + ((size_t)(n0 + r) * 512 + k0 + (lane & 7) * 8) * 2,
                    (char*)&Bs[0][0] + c * 1024);
        }
        __syncthreads();
#pragma unroll
        for (int ks = 0; ks < 2; ++ks) {
            short8 af[4], bf[4];
#pragma unroll
            for (int m = 0; m < 4; ++m)
                af[m] = *(const short8*)(&As[wrow * 64 + m * 16 + li][ks * 32 + lg * 8]);
#pragma unroll
            for (int n = 0; n < 4; ++n)
                bf[n] = *(const short8*)(&Bs[wcol * 64 + n * 16 + li][ks * 32 + lg * 8]);
#pragma unroll
            for (int m = 0; m < 4; ++m)
#pragma unroll
                for (int n = 0; n < 4; ++n)
                    acc[m][n] = __builtin_amdgcn_mfma_f32_16x16x32_bf16(bf[n], af[m], acc[m][n], 0, 0, 0);
        }
        __syncthreads();
    }

    // swapped: lane holds out-row = ...+li, 4 consecutive cols = ...+lg*4+j
    float4 bb[4];
#pragma unroll
    for (int n = 0; n < 4; ++n)
        bb[n] = *(const float4*)(bout + n0 + wcol * 64 + n * 16 + lg * 4);
#pragma unroll
    for (int m = 0; m < 4; ++m) {
        int row = m0 + wrow * 64 + m * 16 + li;
#pragma unroll
        for (int n = 0; n < 4; ++n) {
            int c0 = n0 + wcol * 64 + n * 16 + lg * 4;
            float4 v = { acc[m][n][0] + bb[n].x, acc[m][n][1] + bb[n].y,
                         acc[m][n][2] + bb[n].z, acc[m][n][3] + bb[n].w };
            *(float4*)(out + (size_t)row * 512 + c0) = v;
        }
    }
}

extern "C" void kernel_launch(void* const* d_in, const int* in_sizes, int n_in,
                              void* d_out, int out_size, void* d_ws, size_t ws_size,
                              hipStream_t stream) {
    const float* x    = (const float*)d_in[0];
    const float* bias = (const float*)d_in[1];
    const float* wqkv = (const float*)d_in[2];
    const float* wout = (const float*)d_in[3];
    const float* bout = (const float*)d_in[4];
    float* out = (float*)d_out;
    __hip_bfloat16* ws = (__hip_bfloat16*)d_ws;

    hipLaunchKernelGGL(prep_kernel, dim3(2048), dim3(256), 0, stream, wqkv, wout, x, bias, ws);
    hipLaunchKernelGGL(gemm_qkv, dim3(64, 20), dim3(256), 0, stream, ws);
    hipLaunchKernelGGL(attn_kernel, dim3(512), dim3(256), 0, stream, ws);
    hipLaunchKernelGGL(gemm_out, dim3(64, 4), dim3(256), 0, stream, (const __hip_bfloat16*)ws, bout, out);
}